// Round 12
// baseline (467.669 us; speedup 1.0000x reference)
//
#include <hip/hip_runtime.h>

typedef unsigned short u16;
typedef unsigned int   u32;
typedef __bf16 bfx8 __attribute__((ext_vector_type(8)));
typedef float  fx4  __attribute__((ext_vector_type(4)));

__device__ __forceinline__ u16 f2b(float f) {
    union { float f; u32 i; } v; v.f = f;
    u32 r = (v.i + 0x7fffu + ((v.i >> 16) & 1u)) >> 16;
    return (u16)r;
}
__device__ __forceinline__ u32 pk(float a, float b) {
    return (u32)f2b(a) | ((u32)f2b(b) << 16);
}

__device__ __forceinline__ void gl2lds16(const u16* g, u16* l) {
    __builtin_amdgcn_global_load_lds(
        (const __attribute__((address_space(1))) u32*)(const void*)g,
        (__attribute__((address_space(3))) u32*)(void*)l, 16, 0, 0);
}

// partitioned row r (window-major) -> token index in [0,32768), with roll shift
__device__ __forceinline__ int map_token(int r, int shift) {
    int win = r >> 6, n = r & 63;
    int wh = win >> 6, ww = (win >> 3) & 7, wt = win & 7;
    int h = wh * 4 + (n >> 4);
    int w = ww * 4 + ((n >> 2) & 3);
    int t = wt * 4 + (n & 3);
    h = (h + shift) & 31; w = (w + shift) & 31; t = (t + shift) & 31;
    return (h << 10) | (w << 5) | t;
}

// fast GELU (tanh form): max abs err ~3e-4, hidden under bf16 output rounding
__device__ __forceinline__ float gelu_fast(float v) {
    float t = v * v;
    float u = v * __builtin_fmaf(t, 0.044715f, 1.0f);
    float e = __expf(-1.5957691216057308f * u);
    return v * __builtin_amdgcn_rcpf(1.0f + e);
}

// ---------- batched fp32 -> bf16 weight conversion ----------
struct CvtArgs { const float* src[8]; int cum[9]; };
__global__ __launch_bounds__(256) void cvt_kernel(CvtArgs a, u16* __restrict__ dst) {
    int g = (blockIdx.x * 256 + threadIdx.x) * 4;
    int t = 0;
    #pragma unroll
    for (int i = 1; i < 8; i++) t += (g >= a.cum[i]);
    int local = g - a.cum[t];
    float4 f = *(const float4*)(a.src[t] + local);
    uint2 o; o.x = pk(f.x, f.y); o.y = pk(f.z, f.w);
    *(uint2*)(dst + g) = o;
}

// ---------- LayerNorm (one wave per token) ----------
template<int GATHER, int F32OUT>
__global__ __launch_bounds__(256) void ln_kernel(const float* __restrict__ resid,
                                                 const float* __restrict__ g, const float* __restrict__ b,
                                                 void* __restrict__ outp, int shift) {
    int lane = threadIdx.x & 63;
    int row  = blockIdx.x * 4 + (threadIdx.x >> 6);
    int src  = GATHER ? map_token(row, shift) : row;
    float4 x = ((const float4*)(resid + src * 256))[lane];
    float s1 = x.x + x.y + x.z + x.w;
    float s2 = x.x * x.x + x.y * x.y + x.z * x.z + x.w * x.w;
    #pragma unroll
    for (int off = 1; off < 64; off <<= 1) { s1 += __shfl_xor(s1, off); s2 += __shfl_xor(s2, off); }
    float mean = s1 * (1.0f / 256.0f);
    float var  = s2 * (1.0f / 256.0f) - mean * mean;
    float rstd = rsqrtf(var + 1e-5f);
    int c = lane * 4;
    float4 gv = *(const float4*)(g + c);
    float4 bv = *(const float4*)(b + c);
    float y0 = (x.x - mean) * rstd * gv.x + bv.x;
    float y1 = (x.y - mean) * rstd * gv.y + bv.y;
    float y2 = (x.z - mean) * rstd * gv.z + bv.z;
    float y3 = (x.w - mean) * rstd * gv.w + bv.w;
    if (F32OUT) {
        float4 o; o.x = y0; o.y = y1; o.z = y2; o.w = y3;
        *(float4*)((float*)outp + row * 256 + c) = o;
    } else {
        uint2 o; o.x = pk(y0, y1); o.y = pk(y2, y3);
        *(uint2*)((u16*)outp + row * 256 + c) = o;
    }
}

// ---------- GEMM-128: C[M,N] = A[M,K] @ W[N,K]^T + bias ----------
// 128x128 tile, BK=32, 256 thr / 4 waves. 3-buf depth-2 gl2lds pipeline, one
// barrier per step, counted vmcnt(4). XCD swizzle: xcd=bid&7 owns m-tiles
// [xcd*32,+32), n outer. MEASURED BEST for proj/fc2 (Nout=256) AND fc1 (R8: 42.0us
// vs gemmM 47.6us).
// EPI 0: bf16 store; 1: GELU + bf16 store; 2/3: resid[row] = rsrc[row] + v
template<int EPI>
__global__ __launch_bounds__(256) void gemm2(const u16* __restrict__ A, const u16* __restrict__ W,
                                             const float* __restrict__ bias,
                                             u16* __restrict__ outb, float* __restrict__ resid,
                                             int Nout, int K, int shift,
                                             const float* __restrict__ rsrc) {
    __shared__ u16 As[3][4096];
    __shared__ u16 Bs[3][4096];
    int lane = threadIdx.x & 63, w = threadIdx.x >> 6;
    int wm = w >> 1, wn = w & 1;
    int bid = blockIdx.x;
    int xcd = bid & 7;
    int s   = bid >> 3;
    int m0 = (xcd * 32 + (s & 31)) * 128;
    int n0 = (s >> 5) * 128;
    int lr = lane & 15, q = lane >> 4;
    int sw = q ^ ((lr >> 1) & 3);

    int rowS  = w * 16 + (lane >> 2);
    int kg    = (lane & 3) ^ ((rowS >> 1) & 3);
    int slot0 = (w * 64 + lane) * 8;
    int slot1 = slot0 + 2048;
    const u16* gA0 = A + (size_t)(m0 + rowS) * K + kg * 8;
    const u16* gA1 = A + (size_t)(m0 + rowS + 64) * K + kg * 8;
    const u16* gB0 = W + (size_t)(n0 + rowS) * K + kg * 8;
    const u16* gB1 = W + (size_t)(n0 + rowS + 64) * K + kg * 8;

    int oA[4], oB[4];
    #pragma unroll
    for (int t = 0; t < 4; t++) {
        oA[t] = ((wm * 64 + t * 16 + lr) * 4 + sw) * 8;
        oB[t] = ((wn * 64 + t * 16 + lr) * 4 + sw) * 8;
    }

    fx4 acc[4][4] = {};

    auto stage = [&](int kt, int b) {
        gl2lds16(gA0 + kt, &As[b][slot0]);
        gl2lds16(gA1 + kt, &As[b][slot1]);
        gl2lds16(gB0 + kt, &Bs[b][slot0]);
        gl2lds16(gB1 + kt, &Bs[b][slot1]);
    };

    int nk = K >> 5;
    stage(0, 0);
    if (nk > 1) stage(32, 1);
    int b0 = 0, b1 = 1, b2 = 2;
    for (int ki = 0; ki < nk; ki++) {
        if (ki + 1 < nk) asm volatile("s_waitcnt vmcnt(4)" ::: "memory");
        else             asm volatile("s_waitcnt vmcnt(0)" ::: "memory");
        __builtin_amdgcn_s_barrier();
        __builtin_amdgcn_sched_barrier(0);
        if (ki + 2 < nk) stage((ki + 2) << 5, b2);
        bfx8 af[4], bfr[4];
        #pragma unroll
        for (int t = 0; t < 4; t++) {
            af[t]  = *(const bfx8*)(&As[b0][oA[t]]);
            bfr[t] = *(const bfx8*)(&Bs[b0][oB[t]]);
        }
        #pragma unroll
        for (int i = 0; i < 4; i++)
            #pragma unroll
            for (int j = 0; j < 4; j++)
                acc[i][j] = __builtin_amdgcn_mfma_f32_16x16x32_bf16(af[i], bfr[j], acc[i][j], 0, 0, 0);
        int tmp = b0; b0 = b1; b1 = b2; b2 = tmp;
    }

    float bv[4];
    #pragma unroll
    for (int j = 0; j < 4; j++) bv[j] = bias[n0 + wn * 64 + j * 16 + lr];
    #pragma unroll
    for (int i = 0; i < 4; i++) {
        #pragma unroll
        for (int r = 0; r < 4; r++) {
            int gr = m0 + wm * 64 + i * 16 + q * 4 + r;
            int orow = (EPI == 3) ? map_token(gr, shift) : gr;
            #pragma unroll
            for (int j = 0; j < 4; j++) {
                int gc = n0 + wn * 64 + j * 16 + lr;
                float v = acc[i][j][r] + bv[j];
                if (EPI == 0) {
                    outb[(size_t)gr * Nout + gc] = f2b(v);
                } else if (EPI == 1) {
                    outb[(size_t)gr * Nout + gc] = f2b(gelu_fast(v));
                } else {
                    resid[orow * 256 + gc] = rsrc[orow * 256 + gc] + v;
                }
            }
        }
    }
}

// ---------- GEMM-256: BM=256 x BN=128, BK=32, 512 thr / 8 waves (4m x 2n) ----------
// Same 3-buf one-barrier counted-vmcnt core; 3 gl2lds/stage -> vmcnt(3).
// XCD swizzle: xcd owns m-tiles [xcd*16,+16), n outer.
// MEASURED BEST for qkv (Nout=768; ~6-7us faster than 128-tile per accounting
// across R8/R9/R10 totals). NOT used for fc1 (measured 47.6 vs 42.0 at 128-tile).
template<int EPI>
__global__ __launch_bounds__(512) void gemmM(const u16* __restrict__ A, const u16* __restrict__ W,
                                             const float* __restrict__ bias,
                                             u16* __restrict__ outb, int Nout, int K) {
    __shared__ u16 As[3][8192];   // 256 rows x 32 cols
    __shared__ u16 Bs[3][4096];   // 128 rows x 32 cols
    int tid = threadIdx.x;
    int lane = tid & 63, w = tid >> 6;
    int wm = w >> 1, wn = w & 1;
    int bid = blockIdx.x;
    int xcd = bid & 7;
    int s   = bid >> 3;
    int m0 = (xcd * 16 + (s & 15)) * 256;
    int n0 = (s >> 4) * 128;
    int lr = lane & 15, q = lane >> 4;
    int sw = q ^ ((lr >> 1) & 3);

    int rowS  = tid >> 2;
    int kg    = (tid & 3) ^ ((rowS >> 1) & 3);
    int slotS = tid * 8;
    const u16* gA0 = A + (size_t)(m0 + rowS) * K + kg * 8;
    const u16* gA1 = A + (size_t)(m0 + rowS + 128) * K + kg * 8;
    const u16* gB0 = W + (size_t)(n0 + rowS) * K + kg * 8;

    int oA[4], oB[4];
    #pragma unroll
    for (int t = 0; t < 4; t++) {
        oA[t] = ((wm * 64 + t * 16 + lr) * 4 + sw) * 8;
        oB[t] = ((wn * 64 + t * 16 + lr) * 4 + sw) * 8;
    }

    fx4 acc[4][4] = {};

    auto stage = [&](int kt, int b) {
        gl2lds16(gA0 + kt, &As[b][slotS]);
        gl2lds16(gA1 + kt, &As[b][slotS + 4096]);
        gl2lds16(gB0 + kt, &Bs[b][slotS]);
    };

    int nk = K >> 5;
    stage(0, 0);
    if (nk > 1) stage(32, 1);
    int b0 = 0, b1 = 1, b2 = 2;
    for (int ki = 0; ki < nk; ki++) {
        if (ki + 1 < nk) asm volatile("s_waitcnt vmcnt(3)" ::: "memory");
        else             asm volatile("s_waitcnt vmcnt(0)" ::: "memory");
        __builtin_amdgcn_s_barrier();
        __builtin_amdgcn_sched_barrier(0);
        if (ki + 2 < nk) stage((ki + 2) << 5, b2);
        bfx8 af[4], bfr[4];
        #pragma unroll
        for (int t = 0; t < 4; t++) {
            af[t]  = *(const bfx8*)(&As[b0][oA[t]]);
            bfr[t] = *(const bfx8*)(&Bs[b0][oB[t]]);
        }
        #pragma unroll
        for (int i = 0; i < 4; i++)
            #pragma unroll
            for (int j = 0; j < 4; j++)
                acc[i][j] = __builtin_amdgcn_mfma_f32_16x16x32_bf16(af[i], bfr[j], acc[i][j], 0, 0, 0);
        int tmp = b0; b0 = b1; b1 = b2; b2 = tmp;
    }

    float bv[4];
    #pragma unroll
    for (int j = 0; j < 4; j++) bv[j] = bias[n0 + wn * 64 + j * 16 + lr];
    #pragma unroll
    for (int i = 0; i < 4; i++) {
        #pragma unroll
        for (int r = 0; r < 4; r++) {
            int gr = m0 + wm * 64 + i * 16 + q * 4 + r;
            #pragma unroll
            for (int j = 0; j < 4; j++) {
                int gc = n0 + wn * 64 + j * 16 + lr;
                float v = acc[i][j][r] + bv[j];
                outb[(size_t)gr * Nout + gc] = f2b(EPI == 1 ? gelu_fast(v) : v);
            }
        }
    }
}

// ---------- MFMA attention: one wave per (window, head), 2 waves/block ----------
__global__ __launch_bounds__(128) void attn_mfma(const u16* __restrict__ qkv, const float* __restrict__ rpb,
                                                 u16* __restrict__ outb, int masked) {
    __shared__ u16  Pl[2][64][72];
    __shared__ u16  VT[2][32][72];
    __shared__ float rbS[2][344];
    int w = threadIdx.x >> 6;
    int lane = threadIdx.x & 63;
    int id = blockIdx.x * 2 + w;
    int win = id >> 3, head = id & 7;
    int lr = lane & 15, q = lane >> 4;

    const u16* base = qkv + (size_t)win * 64 * 768 + head * 32;

    bfx8 qf[4], kf[4];
    #pragma unroll
    for (int t = 0; t < 4; t++) {
        const u16* rq = base + (lr + 16 * t) * 768 + q * 8;
        qf[t] = *(const bfx8*)(rq);
        kf[t] = *(const bfx8*)(rq + 256);
    }
    {
        const u16* rv = base + lane * 768 + 512;
        #pragma unroll
        for (int c = 0; c < 32; c += 8) {
            bfx8 vv = *(const bfx8*)(rv + c);
            #pragma unroll
            for (int j = 0; j < 8; j++) VT[w][c + j][lane] = ((const u16*)&vv)[j];
        }
    }
    for (int i = lane; i < 343; i += 64) rbS[w][i] = rpb[i * 8 + head];

    fx4 sT[4][4] = {};
    #pragma unroll
    for (int jt = 0; jt < 4; jt++)
        #pragma unroll
        for (int it = 0; it < 4; it++)
            sT[jt][it] = __builtin_amdgcn_mfma_f32_16x16x32_bf16(kf[jt], qf[it], sT[jt][it], 0, 0, 0);

    int wh = win >> 6, ww = (win >> 3) & 7, wt = win & 7;
    const float scale = 0.17677669529663687f;   // hd^-0.5

    #pragma unroll
    for (int it = 0; it < 4; it++) {
        int i = lr + 16 * it;
        int ih = i >> 4, iw = (i >> 2) & 3, iT = i & 3;
        int labn = 0;
        if (masked) {
            int lh = (wh == 7) ? (1 + (ih >> 1)) : 0;
            int lw = (ww == 7) ? (1 + (iw >> 1)) : 0;
            int lt = (wt == 7) ? (1 + (iT >> 1)) : 0;
            labn = lh * 9 + lw * 3 + lt;
        }
        float sv[4][4];
        float mx = -1e30f;
        #pragma unroll
        for (int jt = 0; jt < 4; jt++)
            #pragma unroll
            for (int r = 0; r < 4; r++) {
                int j = q * 4 + r + 16 * jt;
                int jh = j >> 4, jw = (j >> 2) & 3, jT = j & 3;
                float s = sT[jt][it][r] * scale +
                          rbS[w][((ih - jh + 3) * 7 + (iw - jw + 3)) * 7 + (iT - jT + 3)];
                if (masked) {
                    int lh = (wh == 7) ? (1 + (jh >> 1)) : 0;
                    int lw = (ww == 7) ? (1 + (jw >> 1)) : 0;
                    int lt = (wt == 7) ? (1 + (jT >> 1)) : 0;
                    if (lh * 9 + lw * 3 + lt != labn) s -= 100.0f;
                }
                sv[jt][r] = s;
                mx = fmaxf(mx, s);
            }
        mx = fmaxf(mx, __shfl_xor(mx, 16));
        mx = fmaxf(mx, __shfl_xor(mx, 32));
        float sum = 0.f;
        #pragma unroll
        for (int jt = 0; jt < 4; jt++)
            #pragma unroll
            for (int r = 0; r < 4; r++) { sv[jt][r] = __expf(sv[jt][r] - mx); sum += sv[jt][r]; }
        sum += __shfl_xor(sum, 16);
        sum += __shfl_xor(sum, 32);
        float inv = 1.0f / sum;
        #pragma unroll
        for (int jt = 0; jt < 4; jt++) {
            uint2 pw;
            pw.x = pk(sv[jt][0] * inv, sv[jt][1] * inv);
            pw.y = pk(sv[jt][2] * inv, sv[jt][3] * inv);
            *(uint2*)&Pl[w][i][q * 4 + 16 * jt] = pw;
        }
    }

    fx4 o[4][2] = {};
    #pragma unroll
    for (int kk = 0; kk < 2; kk++) {
        bfx8 pf[4], vf[2];
        #pragma unroll
        for (int it = 0; it < 4; it++) pf[it] = *(const bfx8*)&Pl[w][lr + 16 * it][q * 8 + 32 * kk];
        #pragma unroll
        for (int dt = 0; dt < 2; dt++) vf[dt] = *(const bfx8*)&VT[w][lr + 16 * dt][q * 8 + 32 * kk];
        #pragma unroll
        for (int it = 0; it < 4; it++)
            #pragma unroll
            for (int dt = 0; dt < 2; dt++)
                o[it][dt] = __builtin_amdgcn_mfma_f32_16x16x32_bf16(pf[it], vf[dt], o[it][dt], 0, 0, 0);
    }

    u16* ob = outb + (size_t)win * 64 * 256 + head * 32;
    #pragma unroll
    for (int it = 0; it < 4; it++)
        #pragma unroll
        for (int r = 0; r < 4; r++) {
            int i = 16 * it + q * 4 + r;
            #pragma unroll
            for (int dt = 0; dt < 2; dt++)
                ob[i * 256 + 16 * dt + lr] = f2b(o[it][dt][r]);
        }
}

// ---------- fused final LayerNorm + [L,C] -> [C,L] transpose ----------
__global__ __launch_bounds__(256) void ln_tr(const float* __restrict__ in,
                                             const float* __restrict__ g, const float* __restrict__ b,
                                             float* __restrict__ out) {
    __shared__ float tile[256 * 33];
    int tid = threadIdx.x;
    int r   = tid >> 3;
    int cg  = (tid & 7) * 32;
    int row = blockIdx.x * 32 + r;
    const float* src = in + (size_t)row * 256 + cg;

    float v[32];
    float s1 = 0.f, s2 = 0.f;
    #pragma unroll
    for (int j = 0; j < 8; j++) {
        float4 f = *(const float4*)(src + 4 * j);
        v[4*j] = f.x; v[4*j+1] = f.y; v[4*j+2] = f.z; v[4*j+3] = f.w;
        s1 += f.x + f.y + f.z + f.w;
        s2 += f.x*f.x + f.y*f.y + f.z*f.z + f.w*f.w;
    }
    #pragma unroll
    for (int off = 1; off < 8; off <<= 1) { s1 += __shfl_xor(s1, off); s2 += __shfl_xor(s2, off); }
    float mean = s1 * (1.0f / 256.0f);
    float rstd = rsqrtf(s2 * (1.0f / 256.0f) - mean * mean + 1e-5f);

    #pragma unroll
    for (int j = 0; j < 8; j++) {
        float4 gv = *(const float4*)(g + cg + 4 * j);
        float4 bv = *(const float4*)(b + cg + 4 * j);
        int c0 = cg + 4 * j;
        int slot = (r + (c0 >> 2)) & 31;
        tile[(c0 + 0) * 33 + slot] = (v[4*j]   - mean) * rstd * gv.x + bv.x;
        tile[(c0 + 1) * 33 + slot] = (v[4*j+1] - mean) * rstd * gv.y + bv.y;
        tile[(c0 + 2) * 33 + slot] = (v[4*j+2] - mean) * rstd * gv.z + bv.z;
        tile[(c0 + 3) * 33 + slot] = (v[4*j+3] - mean) * rstd * gv.w + bv.w;
    }
    __syncthreads();

    int c = tid;
    int csh = (c >> 2) & 31;
    const float* base = &tile[c * 33];
    float o[32];
    #pragma unroll
    for (int r2 = 0; r2 < 32; r2++) o[r2] = base[(r2 + csh) & 31];

    float* dst = out + (size_t)c * 32768 + blockIdx.x * 32;
    #pragma unroll
    for (int j = 0; j < 8; j++) {
        float4 f; f.x = o[4*j]; f.y = o[4*j+1]; f.z = o[4*j+2]; f.w = o[4*j+3];
        *(float4*)(dst + 4 * j) = f;
    }
}

extern "C" void kernel_launch(void* const* d_in, const int* in_sizes, int n_in,
                              void* d_out, int out_size, void* d_ws, size_t ws_size,
                              hipStream_t stream) {
    const float* x      = (const float*)d_in[0];
    const float* norm_g = (const float*)d_in[4];
    const float* norm_b = (const float*)d_in[5];

    char* wsb = (char*)d_ws;
    float* resid = (float*)wsb;                                   // [0, 32MB)  fp32 residual
    u16*   xn    = (u16*)(wsb + (size_t)32 * 1024 * 1024);        // [32, 48MB) LN output (bf16)
    u16*   big   = (u16*)(wsb + (size_t)48 * 1024 * 1024);        // [48,112MB) qkv (48MB) / fc1 out (64MB)
    u16*   attnb = (u16*)(wsb + (size_t)96 * 1024 * 1024);        // [96,112MB) attn out (dead before fc1)
    u16*   wb    = (u16*)(wsb + (size_t)112 * 1024 * 1024);       // [112,115MB) bf16 weights

    CvtArgs ca;
    static const int offs[9] = {0, 196608, 262144, 524288, 786432, 983040, 1048576, 1310720, 1572864};
    for (int i = 0; i < 9; i++) ca.cum[i] = offs[i];
    ca.src[0] = (const float*)d_in[6 + 2];   // wqkvw
    ca.src[1] = (const float*)d_in[6 + 5];   // wprojw
    ca.src[2] = (const float*)d_in[6 + 9];   // wfc1w
    ca.src[3] = (const float*)d_in[6 + 11];  // wfc2w
    ca.src[4] = (const float*)d_in[19 + 2];  // sqkvw
    ca.src[5] = (const float*)d_in[19 + 5];  // sprojw
    ca.src[6] = (const float*)d_in[19 + 9];  // sfc1w
    ca.src[7] = (const float*)d_in[19 + 11]; // sfc2w
    cvt_kernel<<<1536, 256, 0, stream>>>(ca, wb);

    for (int blk = 0; blk < 2; blk++) {
        void* const* P = d_in + 6 + blk * 13;
        const float* n1g  = (const float*)P[0];
        const float* n1b  = (const float*)P[1];
        const float* qkvb = (const float*)P[3];
        const float* rpb  = (const float*)P[4];
        const float* pjb  = (const float*)P[6];
        const float* n2g  = (const float*)P[7];
        const float* n2b  = (const float*)P[8];
        const float* f1b  = (const float*)P[10];
        const float* f2b_ = (const float*)P[12];
        const u16* qkvw = wb + offs[0] + blk * 786432;
        const u16* pjw  = wb + offs[1] + blk * 786432;
        const u16* f1w  = wb + offs[2] + blk * 786432;
        const u16* f2w  = wb + offs[3] + blk * 786432;
        int shift = blk ? 2 : 0;

        // blk0: residual not yet materialized -> LN1 reads x directly and the
        // proj epilogue initializes resid = x + proj (saves the 64MB memcpy pass)
        const float* ln1src = blk ? resid : x;
        const float* projadd = blk ? resid : x;

        ln_kernel<1, 0><<<8192, 256, 0, stream>>>(ln1src, n1g, n1b, xn, shift);
        gemmM<0><<<768, 512, 0, stream>>>(xn, qkvw, qkvb, big, 768, 256);
        attn_mfma<<<2048, 128, 0, stream>>>(big, rpb, attnb, blk);
        gemm2<3><<<512, 256, 0, stream>>>(attnb, pjw, pjb, nullptr, resid, 256, 256, shift, projadd);
        ln_kernel<0, 0><<<8192, 256, 0, stream>>>(resid, n2g, n2b, xn, 0);
        gemm2<1><<<2048, 256, 0, stream>>>(xn, f1w, f1b, big, nullptr, 1024, 256, 0, nullptr);
        gemm2<2><<<512, 256, 0, stream>>>(big, f2w, f2b_, nullptr, resid, 256, 1024, 0, resid);
    }

    ln_tr<<<1024, 256, 0, stream>>>(resid, norm_g, norm_b, (float*)d_out);
}

// Round 13
// 452.245 us; speedup vs baseline: 1.0341x; 1.0341x over previous
//
#include <hip/hip_runtime.h>

typedef unsigned short u16;
typedef unsigned int   u32;
typedef __bf16 bfx8 __attribute__((ext_vector_type(8)));
typedef float  fx4  __attribute__((ext_vector_type(4)));

__device__ __forceinline__ u16 f2b(float f) {
    union { float f; u32 i; } v; v.f = f;
    u32 r = (v.i + 0x7fffu + ((v.i >> 16) & 1u)) >> 16;
    return (u16)r;
}
__device__ __forceinline__ float b2f(u16 v) {
    union { u32 i; float f; } u; u.i = ((u32)v) << 16; return u.f;
}
__device__ __forceinline__ u32 pk(float a, float b) {
    return (u32)f2b(a) | ((u32)f2b(b) << 16);
}

__device__ __forceinline__ void gl2lds16(const u16* g, u16* l) {
    __builtin_amdgcn_global_load_lds(
        (const __attribute__((address_space(1))) u32*)(const void*)g,
        (__attribute__((address_space(3))) u32*)(void*)l, 16, 0, 0);
}

// partitioned row r (window-major) -> token index in [0,32768), with roll shift
__device__ __forceinline__ int map_token(int r, int shift) {
    int win = r >> 6, n = r & 63;
    int wh = win >> 6, ww = (win >> 3) & 7, wt = win & 7;
    int h = wh * 4 + (n >> 4);
    int w = ww * 4 + ((n >> 2) & 3);
    int t = wt * 4 + (n & 3);
    h = (h + shift) & 31; w = (w + shift) & 31; t = (t + shift) & 31;
    return (h << 10) | (w << 5) | t;
}

// fast GELU (tanh form): max abs err ~3e-4, hidden under bf16 output rounding
__device__ __forceinline__ float gelu_fast(float v) {
    float t = v * v;
    float u = v * __builtin_fmaf(t, 0.044715f, 1.0f);
    float e = __expf(-1.5957691216057308f * u);
    return v * __builtin_amdgcn_rcpf(1.0f + e);
}

// ---------- batched fp32 -> bf16 weight conversion ----------
struct CvtArgs { const float* src[8]; int cum[9]; };
__global__ __launch_bounds__(256) void cvt_kernel(CvtArgs a, u16* __restrict__ dst) {
    int g = (blockIdx.x * 256 + threadIdx.x) * 4;
    int t = 0;
    #pragma unroll
    for (int i = 1; i < 8; i++) t += (g >= a.cum[i]);
    int local = g - a.cum[t];
    float4 f = *(const float4*)(a.src[t] + local);
    uint2 o; o.x = pk(f.x, f.y); o.y = pk(f.z, f.w);
    *(uint2*)(dst + g) = o;
}

// ---------- LayerNorm (one wave per token) ----------
// INF32: input fp32 (only blk0 LN1 reading x); else input bf16 residual.
template<int GATHER, int INF32>
__global__ __launch_bounds__(256) void ln_kernel(const void* __restrict__ inp,
                                                 const float* __restrict__ g, const float* __restrict__ b,
                                                 u16* __restrict__ outp, int shift) {
    int lane = threadIdx.x & 63;
    int row  = blockIdx.x * 4 + (threadIdx.x >> 6);
    int src  = GATHER ? map_token(row, shift) : row;
    float x0, x1, x2, x3;
    if (INF32) {
        float4 x = ((const float4*)((const float*)inp + (size_t)src * 256))[lane];
        x0 = x.x; x1 = x.y; x2 = x.z; x3 = x.w;
    } else {
        uint2 xb = ((const uint2*)((const u16*)inp + (size_t)src * 256))[lane];
        x0 = b2f((u16)(xb.x & 0xffff)); x1 = b2f((u16)(xb.x >> 16));
        x2 = b2f((u16)(xb.y & 0xffff)); x3 = b2f((u16)(xb.y >> 16));
    }
    float s1 = x0 + x1 + x2 + x3;
    float s2 = x0 * x0 + x1 * x1 + x2 * x2 + x3 * x3;
    #pragma unroll
    for (int off = 1; off < 64; off <<= 1) { s1 += __shfl_xor(s1, off); s2 += __shfl_xor(s2, off); }
    float mean = s1 * (1.0f / 256.0f);
    float var  = s2 * (1.0f / 256.0f) - mean * mean;
    float rstd = rsqrtf(var + 1e-5f);
    int c = lane * 4;
    float4 gv = *(const float4*)(g + c);
    float4 bv = *(const float4*)(b + c);
    uint2 o;
    o.x = pk((x0 - mean) * rstd * gv.x + bv.x, (x1 - mean) * rstd * gv.y + bv.y);
    o.y = pk((x2 - mean) * rstd * gv.z + bv.z, (x3 - mean) * rstd * gv.w + bv.w);
    *(uint2*)(outp + (size_t)row * 256 + c) = o;
}

// ---------- GEMM-128: C[M,N] = A[M,K] @ W[N,K]^T + bias ----------
// 128x128 tile, BK=32, 256 thr / 4 waves. 3-buf depth-2 gl2lds pipeline, one
// barrier per step, counted vmcnt(4). XCD swizzle: xcd=bid&7 owns m-tiles
// [xcd*32,+32), n outer. Used for proj / fc1 / fc2.
// EPI 0: bf16 store; 1: GELU + bf16 store; 2/3: residb[row] = rsrc[row] + v
// (bf16 residual stream; RSF32=1 -> rsrc is fp32 x, else bf16 residb)
template<int EPI, int RSF32>
__global__ __launch_bounds__(256) void gemm2(const u16* __restrict__ A, const u16* __restrict__ W,
                                             const float* __restrict__ bias,
                                             u16* __restrict__ outb, u16* __restrict__ residb,
                                             int Nout, int K, int shift,
                                             const float* __restrict__ rsrcf, const u16* __restrict__ rsrcb) {
    __shared__ u16 As[3][4096];
    __shared__ u16 Bs[3][4096];
    int lane = threadIdx.x & 63, w = threadIdx.x >> 6;
    int wm = w >> 1, wn = w & 1;
    int bid = blockIdx.x;
    int xcd = bid & 7;
    int s   = bid >> 3;
    int m0 = (xcd * 32 + (s & 31)) * 128;
    int n0 = (s >> 5) * 128;
    int lr = lane & 15, q = lane >> 4;
    int sw = q ^ ((lr >> 1) & 3);

    int rowS  = w * 16 + (lane >> 2);
    int kg    = (lane & 3) ^ ((rowS >> 1) & 3);
    int slot0 = (w * 64 + lane) * 8;
    int slot1 = slot0 + 2048;
    const u16* gA0 = A + (size_t)(m0 + rowS) * K + kg * 8;
    const u16* gA1 = A + (size_t)(m0 + rowS + 64) * K + kg * 8;
    const u16* gB0 = W + (size_t)(n0 + rowS) * K + kg * 8;
    const u16* gB1 = W + (size_t)(n0 + rowS + 64) * K + kg * 8;

    int oA[4], oB[4];
    #pragma unroll
    for (int t = 0; t < 4; t++) {
        oA[t] = ((wm * 64 + t * 16 + lr) * 4 + sw) * 8;
        oB[t] = ((wn * 64 + t * 16 + lr) * 4 + sw) * 8;
    }

    fx4 acc[4][4] = {};

    auto stage = [&](int kt, int b) {
        gl2lds16(gA0 + kt, &As[b][slot0]);
        gl2lds16(gA1 + kt, &As[b][slot1]);
        gl2lds16(gB0 + kt, &Bs[b][slot0]);
        gl2lds16(gB1 + kt, &Bs[b][slot1]);
    };

    int nk = K >> 5;
    stage(0, 0);
    if (nk > 1) stage(32, 1);
    int b0 = 0, b1 = 1, b2 = 2;
    for (int ki = 0; ki < nk; ki++) {
        if (ki + 1 < nk) asm volatile("s_waitcnt vmcnt(4)" ::: "memory");
        else             asm volatile("s_waitcnt vmcnt(0)" ::: "memory");
        __builtin_amdgcn_s_barrier();
        __builtin_amdgcn_sched_barrier(0);
        if (ki + 2 < nk) stage((ki + 2) << 5, b2);
        bfx8 af[4], bfr[4];
        #pragma unroll
        for (int t = 0; t < 4; t++) {
            af[t]  = *(const bfx8*)(&As[b0][oA[t]]);
            bfr[t] = *(const bfx8*)(&Bs[b0][oB[t]]);
        }
        #pragma unroll
        for (int i = 0; i < 4; i++)
            #pragma unroll
            for (int j = 0; j < 4; j++)
                acc[i][j] = __builtin_amdgcn_mfma_f32_16x16x32_bf16(af[i], bfr[j], acc[i][j], 0, 0, 0);
        int tmp = b0; b0 = b1; b1 = b2; b2 = tmp;
    }

    float bv[4];
    #pragma unroll
    for (int j = 0; j < 4; j++) bv[j] = bias[n0 + wn * 64 + j * 16 + lr];
    #pragma unroll
    for (int i = 0; i < 4; i++) {
        #pragma unroll
        for (int r = 0; r < 4; r++) {
            int gr = m0 + wm * 64 + i * 16 + q * 4 + r;
            int orow = (EPI == 3) ? map_token(gr, shift) : gr;
            #pragma unroll
            for (int j = 0; j < 4; j++) {
                int gc = n0 + wn * 64 + j * 16 + lr;
                float v = acc[i][j][r] + bv[j];
                if (EPI == 0) {
                    outb[(size_t)gr * Nout + gc] = f2b(v);
                } else if (EPI == 1) {
                    outb[(size_t)gr * Nout + gc] = f2b(gelu_fast(v));
                } else {
                    float rv = RSF32 ? rsrcf[orow * 256 + gc] : b2f(rsrcb[orow * 256 + gc]);
                    residb[orow * 256 + gc] = f2b(rv + v);
                }
            }
        }
    }
}

// ---------- GEMM-256: BM=256 x BN=128, BK=32, 512 thr / 8 waves (4m x 2n) ----------
// Same 3-buf one-barrier counted-vmcnt core; 3 gl2lds/stage -> vmcnt(3).
// XCD swizzle: xcd owns m-tiles [xcd*16,+16), n outer. Used for qkv (Nout=768).
template<int EPI>
__global__ __launch_bounds__(512) void gemmM(const u16* __restrict__ A, const u16* __restrict__ W,
                                             const float* __restrict__ bias,
                                             u16* __restrict__ outb, int Nout, int K) {
    __shared__ u16 As[3][8192];   // 256 rows x 32 cols
    __shared__ u16 Bs[3][4096];   // 128 rows x 32 cols
    int tid = threadIdx.x;
    int lane = tid & 63, w = tid >> 6;
    int wm = w >> 1, wn = w & 1;
    int bid = blockIdx.x;
    int xcd = bid & 7;
    int s   = bid >> 3;
    int m0 = (xcd * 16 + (s & 15)) * 256;
    int n0 = (s >> 4) * 128;
    int lr = lane & 15, q = lane >> 4;
    int sw = q ^ ((lr >> 1) & 3);

    int rowS  = tid >> 2;
    int kg    = (tid & 3) ^ ((rowS >> 1) & 3);
    int slotS = tid * 8;
    const u16* gA0 = A + (size_t)(m0 + rowS) * K + kg * 8;
    const u16* gA1 = A + (size_t)(m0 + rowS + 128) * K + kg * 8;
    const u16* gB0 = W + (size_t)(n0 + rowS) * K + kg * 8;

    int oA[4], oB[4];
    #pragma unroll
    for (int t = 0; t < 4; t++) {
        oA[t] = ((wm * 64 + t * 16 + lr) * 4 + sw) * 8;
        oB[t] = ((wn * 64 + t * 16 + lr) * 4 + sw) * 8;
    }

    fx4 acc[4][4] = {};

    auto stage = [&](int kt, int b) {
        gl2lds16(gA0 + kt, &As[b][slotS]);
        gl2lds16(gA1 + kt, &As[b][slotS + 4096]);
        gl2lds16(gB0 + kt, &Bs[b][slotS]);
    };

    int nk = K >> 5;
    stage(0, 0);
    if (nk > 1) stage(32, 1);
    int b0 = 0, b1 = 1, b2 = 2;
    for (int ki = 0; ki < nk; ki++) {
        if (ki + 1 < nk) asm volatile("s_waitcnt vmcnt(3)" ::: "memory");
        else             asm volatile("s_waitcnt vmcnt(0)" ::: "memory");
        __builtin_amdgcn_s_barrier();
        __builtin_amdgcn_sched_barrier(0);
        if (ki + 2 < nk) stage((ki + 2) << 5, b2);
        bfx8 af[4], bfr[4];
        #pragma unroll
        for (int t = 0; t < 4; t++) {
            af[t]  = *(const bfx8*)(&As[b0][oA[t]]);
            bfr[t] = *(const bfx8*)(&Bs[b0][oB[t]]);
        }
        #pragma unroll
        for (int i = 0; i < 4; i++)
            #pragma unroll
            for (int j = 0; j < 4; j++)
                acc[i][j] = __builtin_amdgcn_mfma_f32_16x16x32_bf16(af[i], bfr[j], acc[i][j], 0, 0, 0);
        int tmp = b0; b0 = b1; b1 = b2; b2 = tmp;
    }

    float bv[4];
    #pragma unroll
    for (int j = 0; j < 4; j++) bv[j] = bias[n0 + wn * 64 + j * 16 + lr];
    #pragma unroll
    for (int i = 0; i < 4; i++) {
        #pragma unroll
        for (int r = 0; r < 4; r++) {
            int gr = m0 + wm * 64 + i * 16 + q * 4 + r;
            #pragma unroll
            for (int j = 0; j < 4; j++) {
                int gc = n0 + wn * 64 + j * 16 + lr;
                float v = acc[i][j][r] + bv[j];
                outb[(size_t)gr * Nout + gc] = f2b(EPI == 1 ? gelu_fast(v) : v);
            }
        }
    }
}

// ---------- MFMA attention: one wave per (window, head), 2 waves/block ----------
__global__ __launch_bounds__(128) void attn_mfma(const u16* __restrict__ qkv, const float* __restrict__ rpb,
                                                 u16* __restrict__ outb, int masked) {
    __shared__ u16  Pl[2][64][72];
    __shared__ u16  VT[2][32][72];
    __shared__ float rbS[2][344];
    int w = threadIdx.x >> 6;
    int lane = threadIdx.x & 63;
    int id = blockIdx.x * 2 + w;
    int win = id >> 3, head = id & 7;
    int lr = lane & 15, q = lane >> 4;

    const u16* base = qkv + (size_t)win * 64 * 768 + head * 32;

    bfx8 qf[4], kf[4];
    #pragma unroll
    for (int t = 0; t < 4; t++) {
        const u16* rq = base + (lr + 16 * t) * 768 + q * 8;
        qf[t] = *(const bfx8*)(rq);
        kf[t] = *(const bfx8*)(rq + 256);
    }
    {
        const u16* rv = base + lane * 768 + 512;
        #pragma unroll
        for (int c = 0; c < 32; c += 8) {
            bfx8 vv = *(const bfx8*)(rv + c);
            #pragma unroll
            for (int j = 0; j < 8; j++) VT[w][c + j][lane] = ((const u16*)&vv)[j];
        }
    }
    for (int i = lane; i < 343; i += 64) rbS[w][i] = rpb[i * 8 + head];

    fx4 sT[4][4] = {};
    #pragma unroll
    for (int jt = 0; jt < 4; jt++)
        #pragma unroll
        for (int it = 0; it < 4; it++)
            sT[jt][it] = __builtin_amdgcn_mfma_f32_16x16x32_bf16(kf[jt], qf[it], sT[jt][it], 0, 0, 0);

    int wh = win >> 6, ww = (win >> 3) & 7, wt = win & 7;
    const float scale = 0.17677669529663687f;   // hd^-0.5

    #pragma unroll
    for (int it = 0; it < 4; it++) {
        int i = lr + 16 * it;
        int ih = i >> 4, iw = (i >> 2) & 3, iT = i & 3;
        int labn = 0;
        if (masked) {
            int lh = (wh == 7) ? (1 + (ih >> 1)) : 0;
            int lw = (ww == 7) ? (1 + (iw >> 1)) : 0;
            int lt = (wt == 7) ? (1 + (iT >> 1)) : 0;
            labn = lh * 9 + lw * 3 + lt;
        }
        float sv[4][4];
        float mx = -1e30f;
        #pragma unroll
        for (int jt = 0; jt < 4; jt++)
            #pragma unroll
            for (int r = 0; r < 4; r++) {
                int j = q * 4 + r + 16 * jt;
                int jh = j >> 4, jw = (j >> 2) & 3, jT = j & 3;
                float s = sT[jt][it][r] * scale +
                          rbS[w][((ih - jh + 3) * 7 + (iw - jw + 3)) * 7 + (iT - jT + 3)];
                if (masked) {
                    int lh = (wh == 7) ? (1 + (jh >> 1)) : 0;
                    int lw = (ww == 7) ? (1 + (jw >> 1)) : 0;
                    int lt = (wt == 7) ? (1 + (jT >> 1)) : 0;
                    if (lh * 9 + lw * 3 + lt != labn) s -= 100.0f;
                }
                sv[jt][r] = s;
                mx = fmaxf(mx, s);
            }
        mx = fmaxf(mx, __shfl_xor(mx, 16));
        mx = fmaxf(mx, __shfl_xor(mx, 32));
        float sum = 0.f;
        #pragma unroll
        for (int jt = 0; jt < 4; jt++)
            #pragma unroll
            for (int r = 0; r < 4; r++) { sv[jt][r] = __expf(sv[jt][r] - mx); sum += sv[jt][r]; }
        sum += __shfl_xor(sum, 16);
        sum += __shfl_xor(sum, 32);
        float inv = 1.0f / sum;
        #pragma unroll
        for (int jt = 0; jt < 4; jt++) {
            uint2 pw;
            pw.x = pk(sv[jt][0] * inv, sv[jt][1] * inv);
            pw.y = pk(sv[jt][2] * inv, sv[jt][3] * inv);
            *(uint2*)&Pl[w][i][q * 4 + 16 * jt] = pw;
        }
    }

    fx4 o[4][2] = {};
    #pragma unroll
    for (int kk = 0; kk < 2; kk++) {
        bfx8 pf[4], vf[2];
        #pragma unroll
        for (int it = 0; it < 4; it++) pf[it] = *(const bfx8*)&Pl[w][lr + 16 * it][q * 8 + 32 * kk];
        #pragma unroll
        for (int dt = 0; dt < 2; dt++) vf[dt] = *(const bfx8*)&VT[w][lr + 16 * dt][q * 8 + 32 * kk];
        #pragma unroll
        for (int it = 0; it < 4; it++)
            #pragma unroll
            for (int dt = 0; dt < 2; dt++)
                o[it][dt] = __builtin_amdgcn_mfma_f32_16x16x32_bf16(pf[it], vf[dt], o[it][dt], 0, 0, 0);
    }

    u16* ob = outb + (size_t)win * 64 * 256 + head * 32;
    #pragma unroll
    for (int it = 0; it < 4; it++)
        #pragma unroll
        for (int r = 0; r < 4; r++) {
            int i = 16 * it + q * 4 + r;
            #pragma unroll
            for (int dt = 0; dt < 2; dt++)
                ob[i * 256 + 16 * dt + lr] = f2b(o[it][dt][r]);
        }
}

// ---------- fused final LayerNorm + [L,C] -> [C,L] transpose (bf16 residual in) ----------
__global__ __launch_bounds__(256) void ln_tr(const u16* __restrict__ in,
                                             const float* __restrict__ g, const float* __restrict__ b,
                                             float* __restrict__ out) {
    __shared__ float tile[256 * 33];
    int tid = threadIdx.x;
    int r   = tid >> 3;
    int cg  = (tid & 7) * 32;
    int row = blockIdx.x * 32 + r;
    const u16* src = in + (size_t)row * 256 + cg;

    float v[32];
    float s1 = 0.f, s2 = 0.f;
    #pragma unroll
    for (int j = 0; j < 4; j++) {
        uint4 f = *(const uint4*)(src + 8 * j);
        u32 ws[4] = {f.x, f.y, f.z, f.w};
        #pragma unroll
        for (int k = 0; k < 4; k++) {
            float a = b2f((u16)(ws[k] & 0xffff));
            float c2 = b2f((u16)(ws[k] >> 16));
            v[8 * j + 2 * k] = a; v[8 * j + 2 * k + 1] = c2;
            s1 += a + c2;
            s2 += a * a + c2 * c2;
        }
    }
    #pragma unroll
    for (int off = 1; off < 8; off <<= 1) { s1 += __shfl_xor(s1, off); s2 += __shfl_xor(s2, off); }
    float mean = s1 * (1.0f / 256.0f);
    float rstd = rsqrtf(s2 * (1.0f / 256.0f) - mean * mean + 1e-5f);

    #pragma unroll
    for (int j = 0; j < 8; j++) {
        float4 gv = *(const float4*)(g + cg + 4 * j);
        float4 bv = *(const float4*)(b + cg + 4 * j);
        int c0 = cg + 4 * j;
        int slot = (r + (c0 >> 2)) & 31;
        tile[(c0 + 0) * 33 + slot] = (v[4*j]   - mean) * rstd * gv.x + bv.x;
        tile[(c0 + 1) * 33 + slot] = (v[4*j+1] - mean) * rstd * gv.y + bv.y;
        tile[(c0 + 2) * 33 + slot] = (v[4*j+2] - mean) * rstd * gv.z + bv.z;
        tile[(c0 + 3) * 33 + slot] = (v[4*j+3] - mean) * rstd * gv.w + bv.w;
    }
    __syncthreads();

    int c = tid;
    int csh = (c >> 2) & 31;
    const float* base = &tile[c * 33];
    float o[32];
    #pragma unroll
    for (int r2 = 0; r2 < 32; r2++) o[r2] = base[(r2 + csh) & 31];

    float* dst = out + (size_t)c * 32768 + blockIdx.x * 32;
    #pragma unroll
    for (int j = 0; j < 8; j++) {
        float4 f; f.x = o[4*j]; f.y = o[4*j+1]; f.z = o[4*j+2]; f.w = o[4*j+3];
        *(float4*)(dst + 4 * j) = f;
    }
}

extern "C" void kernel_launch(void* const* d_in, const int* in_sizes, int n_in,
                              void* d_out, int out_size, void* d_ws, size_t ws_size,
                              hipStream_t stream) {
    const float* x      = (const float*)d_in[0];
    const float* norm_g = (const float*)d_in[4];
    const float* norm_b = (const float*)d_in[5];

    char* wsb = (char*)d_ws;
    u16*   residb = (u16*)wsb;                                    // [0, 16MB)  bf16 residual
    u16*   xn     = (u16*)(wsb + (size_t)32 * 1024 * 1024);       // [32, 48MB) LN output (bf16)
    u16*   big    = (u16*)(wsb + (size_t)48 * 1024 * 1024);       // [48,112MB) qkv (48MB) / fc1 out (64MB)
    u16*   attnb  = (u16*)(wsb + (size_t)96 * 1024 * 1024);       // [96,112MB) attn out (dead before fc1)
    u16*   wb     = (u16*)(wsb + (size_t)112 * 1024 * 1024);      // [112,115MB) bf16 weights

    CvtArgs ca;
    static const int offs[9] = {0, 196608, 262144, 524288, 786432, 983040, 1048576, 1310720, 1572864};
    for (int i = 0; i < 9; i++) ca.cum[i] = offs[i];
    ca.src[0] = (const float*)d_in[6 + 2];   // wqkvw
    ca.src[1] = (const float*)d_in[6 + 5];   // wprojw
    ca.src[2] = (const float*)d_in[6 + 9];   // wfc1w
    ca.src[3] = (const float*)d_in[6 + 11];  // wfc2w
    ca.src[4] = (const float*)d_in[19 + 2];  // sqkvw
    ca.src[5] = (const float*)d_in[19 + 5];  // sprojw
    ca.src[6] = (const float*)d_in[19 + 9];  // sfc1w
    ca.src[7] = (const float*)d_in[19 + 11]; // sfc2w
    cvt_kernel<<<1536, 256, 0, stream>>>(ca, wb);

    for (int blk = 0; blk < 2; blk++) {
        void* const* P = d_in + 6 + blk * 13;
        const float* n1g  = (const float*)P[0];
        const float* n1b  = (const float*)P[1];
        const float* qkvb = (const float*)P[3];
        const float* rpb  = (const float*)P[4];
        const float* pjb  = (const float*)P[6];
        const float* n2g  = (const float*)P[7];
        const float* n2b  = (const float*)P[8];
        const float* f1b  = (const float*)P[10];
        const float* f2b_ = (const float*)P[12];
        const u16* qkvw = wb + offs[0] + blk * 786432;
        const u16* pjw  = wb + offs[1] + blk * 786432;
        const u16* f1w  = wb + offs[2] + blk * 786432;
        const u16* f2w  = wb + offs[3] + blk * 786432;
        int shift = blk ? 2 : 0;

        // blk0: LN1 reads x (fp32) directly; proj epilogue seeds residb = x + proj.
        if (blk == 0) {
            ln_kernel<1, 1><<<8192, 256, 0, stream>>>(x, n1g, n1b, xn, shift);
        } else {
            ln_kernel<1, 0><<<8192, 256, 0, stream>>>(residb, n1g, n1b, xn, shift);
        }
        gemmM<0><<<768, 512, 0, stream>>>(xn, qkvw, qkvb, big, 768, 256);
        attn_mfma<<<2048, 128, 0, stream>>>(big, rpb, attnb, blk);
        if (blk == 0) {
            gemm2<3, 1><<<512, 256, 0, stream>>>(attnb, pjw, pjb, nullptr, residb, 256, 256, shift, x, nullptr);
        } else {
            gemm2<3, 0><<<512, 256, 0, stream>>>(attnb, pjw, pjb, nullptr, residb, 256, 256, shift, nullptr, residb);
        }
        ln_kernel<0, 0><<<8192, 256, 0, stream>>>(residb, n2g, n2b, xn, 0);
        gemm2<1, 0><<<2048, 256, 0, stream>>>(xn, f1w, f1b, big, nullptr, 1024, 256, 0, nullptr, nullptr);
        gemm2<2, 0><<<512, 256, 0, stream>>>(big, f2w, f2b_, nullptr, residb, 256, 1024, 0, nullptr, residb);
    }

    ln_tr<<<1024, 256, 0, stream>>>(residb, norm_g, norm_b, (float*)d_out);
}

// Round 14
// 449.094 us; speedup vs baseline: 1.0414x; 1.0070x over previous
//
#include <hip/hip_runtime.h>

typedef unsigned short u16;
typedef unsigned int   u32;
typedef __bf16 bfx8 __attribute__((ext_vector_type(8)));
typedef float  fx4  __attribute__((ext_vector_type(4)));

// single-instruction packed f32->bf16 (RNE), gfx950
__device__ __forceinline__ u32 pk(float a, float b) {
    u32 r;
    asm("v_cvt_pk_bf16_f32 %0, %1, %2" : "=v"(r) : "v"(a), "v"(b));
    return r;
}
__device__ __forceinline__ u16 f2b(float f) {
    return (u16)pk(f, f);
}
__device__ __forceinline__ float b2f(u16 v) {
    union { u32 i; float f; } u; u.i = ((u32)v) << 16; return u.f;
}

__device__ __forceinline__ void gl2lds16(const u16* g, u16* l) {
    __builtin_amdgcn_global_load_lds(
        (const __attribute__((address_space(1))) u32*)(const void*)g,
        (__attribute__((address_space(3))) u32*)(void*)l, 16, 0, 0);
}

// partitioned row r (window-major) -> token index in [0,32768), with roll shift
__device__ __forceinline__ int map_token(int r, int shift) {
    int win = r >> 6, n = r & 63;
    int wh = win >> 6, ww = (win >> 3) & 7, wt = win & 7;
    int h = wh * 4 + (n >> 4);
    int w = ww * 4 + ((n >> 2) & 3);
    int t = wt * 4 + (n & 3);
    h = (h + shift) & 31; w = (w + shift) & 31; t = (t + shift) & 31;
    return (h << 10) | (w << 5) | t;
}

// fast GELU (tanh form): max abs err ~3e-4, hidden under bf16 output rounding
__device__ __forceinline__ float gelu_fast(float v) {
    float t = v * v;
    float u = v * __builtin_fmaf(t, 0.044715f, 1.0f);
    float e = __expf(-1.5957691216057308f * u);
    return v * __builtin_amdgcn_rcpf(1.0f + e);
}

// ---------- batched fp32 -> bf16 weight conversion ----------
struct CvtArgs { const float* src[8]; int cum[9]; };
__global__ __launch_bounds__(256) void cvt_kernel(CvtArgs a, u16* __restrict__ dst) {
    int g = (blockIdx.x * 256 + threadIdx.x) * 4;
    int t = 0;
    #pragma unroll
    for (int i = 1; i < 8; i++) t += (g >= a.cum[i]);
    int local = g - a.cum[t];
    float4 f = *(const float4*)(a.src[t] + local);
    uint2 o; o.x = pk(f.x, f.y); o.y = pk(f.z, f.w);
    *(uint2*)(dst + g) = o;
}

// ---------- LayerNorm (one wave per token) ----------
// INF32: input fp32 (only blk0 LN1 reading x); else input bf16 residual.
template<int GATHER, int INF32>
__global__ __launch_bounds__(256) void ln_kernel(const void* __restrict__ inp,
                                                 const float* __restrict__ g, const float* __restrict__ b,
                                                 u16* __restrict__ outp, int shift) {
    int lane = threadIdx.x & 63;
    int row  = blockIdx.x * 4 + (threadIdx.x >> 6);
    int src  = GATHER ? map_token(row, shift) : row;
    float x0, x1, x2, x3;
    if (INF32) {
        float4 x = ((const float4*)((const float*)inp + (size_t)src * 256))[lane];
        x0 = x.x; x1 = x.y; x2 = x.z; x3 = x.w;
    } else {
        uint2 xb = ((const uint2*)((const u16*)inp + (size_t)src * 256))[lane];
        x0 = b2f((u16)(xb.x & 0xffff)); x1 = b2f((u16)(xb.x >> 16));
        x2 = b2f((u16)(xb.y & 0xffff)); x3 = b2f((u16)(xb.y >> 16));
    }
    float s1 = x0 + x1 + x2 + x3;
    float s2 = x0 * x0 + x1 * x1 + x2 * x2 + x3 * x3;
    #pragma unroll
    for (int off = 1; off < 64; off <<= 1) { s1 += __shfl_xor(s1, off); s2 += __shfl_xor(s2, off); }
    float mean = s1 * (1.0f / 256.0f);
    float var  = s2 * (1.0f / 256.0f) - mean * mean;
    float rstd = rsqrtf(var + 1e-5f);
    int c = lane * 4;
    float4 gv = *(const float4*)(g + c);
    float4 bv = *(const float4*)(b + c);
    uint2 o;
    o.x = pk((x0 - mean) * rstd * gv.x + bv.x, (x1 - mean) * rstd * gv.y + bv.y);
    o.y = pk((x2 - mean) * rstd * gv.z + bv.z, (x3 - mean) * rstd * gv.w + bv.w);
    *(uint2*)(outp + (size_t)row * 256 + c) = o;
}

// ---------- GEMM-128: C[M,N] = A[M,K] @ W[N,K]^T + bias ----------
// 128x128 tile, BK=32, 256 thr / 4 waves. 3-buf depth-2 gl2lds pipeline, one
// barrier per step, counted vmcnt(4). XCD swizzle: xcd=bid&7 owns m-tiles
// [xcd*32,+32), n outer. Used for proj / fc1 / fc2.
// EPI 0: bf16 store; 1: GELU + bf16 store; 2/3: residb[row] = rsrc[row] + v
// (bf16 residual stream; RSF32=1 -> rsrc is fp32 x, else bf16 residb)
template<int EPI, int RSF32>
__global__ __launch_bounds__(256) void gemm2(const u16* __restrict__ A, const u16* __restrict__ W,
                                             const float* __restrict__ bias,
                                             u16* __restrict__ outb, u16* __restrict__ residb,
                                             int Nout, int K, int shift,
                                             const float* __restrict__ rsrcf, const u16* __restrict__ rsrcb) {
    __shared__ u16 As[3][4096];
    __shared__ u16 Bs[3][4096];
    int lane = threadIdx.x & 63, w = threadIdx.x >> 6;
    int wm = w >> 1, wn = w & 1;
    int bid = blockIdx.x;
    int xcd = bid & 7;
    int s   = bid >> 3;
    int m0 = (xcd * 32 + (s & 31)) * 128;
    int n0 = (s >> 5) * 128;
    int lr = lane & 15, q = lane >> 4;
    int sw = q ^ ((lr >> 1) & 3);

    int rowS  = w * 16 + (lane >> 2);
    int kg    = (lane & 3) ^ ((rowS >> 1) & 3);
    int slot0 = (w * 64 + lane) * 8;
    int slot1 = slot0 + 2048;
    const u16* gA0 = A + (size_t)(m0 + rowS) * K + kg * 8;
    const u16* gA1 = A + (size_t)(m0 + rowS + 64) * K + kg * 8;
    const u16* gB0 = W + (size_t)(n0 + rowS) * K + kg * 8;
    const u16* gB1 = W + (size_t)(n0 + rowS + 64) * K + kg * 8;

    int oA[4], oB[4];
    #pragma unroll
    for (int t = 0; t < 4; t++) {
        oA[t] = ((wm * 64 + t * 16 + lr) * 4 + sw) * 8;
        oB[t] = ((wn * 64 + t * 16 + lr) * 4 + sw) * 8;
    }

    fx4 acc[4][4] = {};

    auto stage = [&](int kt, int b) {
        gl2lds16(gA0 + kt, &As[b][slot0]);
        gl2lds16(gA1 + kt, &As[b][slot1]);
        gl2lds16(gB0 + kt, &Bs[b][slot0]);
        gl2lds16(gB1 + kt, &Bs[b][slot1]);
    };

    int nk = K >> 5;
    stage(0, 0);
    if (nk > 1) stage(32, 1);
    int b0 = 0, b1 = 1, b2 = 2;
    for (int ki = 0; ki < nk; ki++) {
        if (ki + 1 < nk) asm volatile("s_waitcnt vmcnt(4)" ::: "memory");
        else             asm volatile("s_waitcnt vmcnt(0)" ::: "memory");
        __builtin_amdgcn_s_barrier();
        __builtin_amdgcn_sched_barrier(0);
        if (ki + 2 < nk) stage((ki + 2) << 5, b2);
        bfx8 af[4], bfr[4];
        #pragma unroll
        for (int t = 0; t < 4; t++) {
            af[t]  = *(const bfx8*)(&As[b0][oA[t]]);
            bfr[t] = *(const bfx8*)(&Bs[b0][oB[t]]);
        }
        #pragma unroll
        for (int i = 0; i < 4; i++)
            #pragma unroll
            for (int j = 0; j < 4; j++)
                acc[i][j] = __builtin_amdgcn_mfma_f32_16x16x32_bf16(af[i], bfr[j], acc[i][j], 0, 0, 0);
        int tmp = b0; b0 = b1; b1 = b2; b2 = tmp;
    }

    float bv[4];
    #pragma unroll
    for (int j = 0; j < 4; j++) bv[j] = bias[n0 + wn * 64 + j * 16 + lr];
    #pragma unroll
    for (int i = 0; i < 4; i++) {
        #pragma unroll
        for (int r = 0; r < 4; r++) {
            int gr = m0 + wm * 64 + i * 16 + q * 4 + r;
            int orow = (EPI == 3) ? map_token(gr, shift) : gr;
            #pragma unroll
            for (int j = 0; j < 4; j++) {
                int gc = n0 + wn * 64 + j * 16 + lr;
                float v = acc[i][j][r] + bv[j];
                if (EPI == 0) {
                    outb[(size_t)gr * Nout + gc] = f2b(v);
                } else if (EPI == 1) {
                    outb[(size_t)gr * Nout + gc] = f2b(gelu_fast(v));
                } else {
                    float rv = RSF32 ? rsrcf[orow * 256 + gc] : b2f(rsrcb[orow * 256 + gc]);
                    residb[orow * 256 + gc] = f2b(rv + v);
                }
            }
        }
    }
}

// ---------- GEMM-256: BM=256 x BN=128, BK=32, 512 thr / 8 waves (4m x 2n) ----------
// Same 3-buf one-barrier counted-vmcnt core; 3 gl2lds/stage -> vmcnt(3).
// XCD swizzle: xcd owns m-tiles [xcd*16,+16), n outer. Used for qkv (Nout=768).
template<int EPI>
__global__ __launch_bounds__(512) void gemmM(const u16* __restrict__ A, const u16* __restrict__ W,
                                             const float* __restrict__ bias,
                                             u16* __restrict__ outb, int Nout, int K) {
    __shared__ u16 As[3][8192];   // 256 rows x 32 cols
    __shared__ u16 Bs[3][4096];   // 128 rows x 32 cols
    int tid = threadIdx.x;
    int lane = tid & 63, w = tid >> 6;
    int wm = w >> 1, wn = w & 1;
    int bid = blockIdx.x;
    int xcd = bid & 7;
    int s   = bid >> 3;
    int m0 = (xcd * 16 + (s & 15)) * 256;
    int n0 = (s >> 4) * 128;
    int lr = lane & 15, q = lane >> 4;
    int sw = q ^ ((lr >> 1) & 3);

    int rowS  = tid >> 2;
    int kg    = (tid & 3) ^ ((rowS >> 1) & 3);
    int slotS = tid * 8;
    const u16* gA0 = A + (size_t)(m0 + rowS) * K + kg * 8;
    const u16* gA1 = A + (size_t)(m0 + rowS + 128) * K + kg * 8;
    const u16* gB0 = W + (size_t)(n0 + rowS) * K + kg * 8;

    int oA[4], oB[4];
    #pragma unroll
    for (int t = 0; t < 4; t++) {
        oA[t] = ((wm * 64 + t * 16 + lr) * 4 + sw) * 8;
        oB[t] = ((wn * 64 + t * 16 + lr) * 4 + sw) * 8;
    }

    fx4 acc[4][4] = {};

    auto stage = [&](int kt, int b) {
        gl2lds16(gA0 + kt, &As[b][slotS]);
        gl2lds16(gA1 + kt, &As[b][slotS + 4096]);
        gl2lds16(gB0 + kt, &Bs[b][slotS]);
    };

    int nk = K >> 5;
    stage(0, 0);
    if (nk > 1) stage(32, 1);
    int b0 = 0, b1 = 1, b2 = 2;
    for (int ki = 0; ki < nk; ki++) {
        if (ki + 1 < nk) asm volatile("s_waitcnt vmcnt(3)" ::: "memory");
        else             asm volatile("s_waitcnt vmcnt(0)" ::: "memory");
        __builtin_amdgcn_s_barrier();
        __builtin_amdgcn_sched_barrier(0);
        if (ki + 2 < nk) stage((ki + 2) << 5, b2);
        bfx8 af[4], bfr[4];
        #pragma unroll
        for (int t = 0; t < 4; t++) {
            af[t]  = *(const bfx8*)(&As[b0][oA[t]]);
            bfr[t] = *(const bfx8*)(&Bs[b0][oB[t]]);
        }
        #pragma unroll
        for (int i = 0; i < 4; i++)
            #pragma unroll
            for (int j = 0; j < 4; j++)
                acc[i][j] = __builtin_amdgcn_mfma_f32_16x16x32_bf16(af[i], bfr[j], acc[i][j], 0, 0, 0);
        int tmp = b0; b0 = b1; b1 = b2; b2 = tmp;
    }

    float bv[4];
    #pragma unroll
    for (int j = 0; j < 4; j++) bv[j] = bias[n0 + wn * 64 + j * 16 + lr];
    #pragma unroll
    for (int i = 0; i < 4; i++) {
        #pragma unroll
        for (int r = 0; r < 4; r++) {
            int gr = m0 + wm * 64 + i * 16 + q * 4 + r;
            #pragma unroll
            for (int j = 0; j < 4; j++) {
                int gc = n0 + wn * 64 + j * 16 + lr;
                float v = acc[i][j][r] + bv[j];
                outb[(size_t)gr * Nout + gc] = f2b(EPI == 1 ? gelu_fast(v) : v);
            }
        }
    }
}

// ---------- MFMA attention: one wave per (window, head), 2 waves/block ----------
__global__ __launch_bounds__(128) void attn_mfma(const u16* __restrict__ qkv, const float* __restrict__ rpb,
                                                 u16* __restrict__ outb, int masked) {
    __shared__ u16  Pl[2][64][72];
    __shared__ u16  VT[2][32][72];
    __shared__ float rbS[2][344];
    int w = threadIdx.x >> 6;
    int lane = threadIdx.x & 63;
    int id = blockIdx.x * 2 + w;
    int win = id >> 3, head = id & 7;
    int lr = lane & 15, q = lane >> 4;

    const u16* base = qkv + (size_t)win * 64 * 768 + head * 32;

    bfx8 qf[4], kf[4];
    #pragma unroll
    for (int t = 0; t < 4; t++) {
        const u16* rq = base + (lr + 16 * t) * 768 + q * 8;
        qf[t] = *(const bfx8*)(rq);
        kf[t] = *(const bfx8*)(rq + 256);
    }
    {
        const u16* rv = base + lane * 768 + 512;
        #pragma unroll
        for (int c = 0; c < 32; c += 8) {
            bfx8 vv = *(const bfx8*)(rv + c);
            #pragma unroll
            for (int j = 0; j < 8; j++) VT[w][c + j][lane] = ((const u16*)&vv)[j];
        }
    }
    for (int i = lane; i < 343; i += 64) rbS[w][i] = rpb[i * 8 + head];

    fx4 sT[4][4] = {};
    #pragma unroll
    for (int jt = 0; jt < 4; jt++)
        #pragma unroll
        for (int it = 0; it < 4; it++)
            sT[jt][it] = __builtin_amdgcn_mfma_f32_16x16x32_bf16(kf[jt], qf[it], sT[jt][it], 0, 0, 0);

    int wh = win >> 6, ww = (win >> 3) & 7, wt = win & 7;
    const float scale = 0.17677669529663687f;   // hd^-0.5

    #pragma unroll
    for (int it = 0; it < 4; it++) {
        int i = lr + 16 * it;
        int ih = i >> 4, iw = (i >> 2) & 3, iT = i & 3;
        int labn = 0;
        if (masked) {
            int lh = (wh == 7) ? (1 + (ih >> 1)) : 0;
            int lw = (ww == 7) ? (1 + (iw >> 1)) : 0;
            int lt = (wt == 7) ? (1 + (iT >> 1)) : 0;
            labn = lh * 9 + lw * 3 + lt;
        }
        float sv[4][4];
        float mx = -1e30f;
        #pragma unroll
        for (int jt = 0; jt < 4; jt++)
            #pragma unroll
            for (int r = 0; r < 4; r++) {
                int j = q * 4 + r + 16 * jt;
                int jh = j >> 4, jw = (j >> 2) & 3, jT = j & 3;
                float s = sT[jt][it][r] * scale +
                          rbS[w][((ih - jh + 3) * 7 + (iw - jw + 3)) * 7 + (iT - jT + 3)];
                if (masked) {
                    int lh = (wh == 7) ? (1 + (jh >> 1)) : 0;
                    int lw = (ww == 7) ? (1 + (jw >> 1)) : 0;
                    int lt = (wt == 7) ? (1 + (jT >> 1)) : 0;
                    if (lh * 9 + lw * 3 + lt != labn) s -= 100.0f;
                }
                sv[jt][r] = s;
                mx = fmaxf(mx, s);
            }
        mx = fmaxf(mx, __shfl_xor(mx, 16));
        mx = fmaxf(mx, __shfl_xor(mx, 32));
        float sum = 0.f;
        #pragma unroll
        for (int jt = 0; jt < 4; jt++)
            #pragma unroll
            for (int r = 0; r < 4; r++) { sv[jt][r] = __expf(sv[jt][r] - mx); sum += sv[jt][r]; }
        sum += __shfl_xor(sum, 16);
        sum += __shfl_xor(sum, 32);
        float inv = 1.0f / sum;
        #pragma unroll
        for (int jt = 0; jt < 4; jt++) {
            uint2 pw;
            pw.x = pk(sv[jt][0] * inv, sv[jt][1] * inv);
            pw.y = pk(sv[jt][2] * inv, sv[jt][3] * inv);
            *(uint2*)&Pl[w][i][q * 4 + 16 * jt] = pw;
        }
    }

    fx4 o[4][2] = {};
    #pragma unroll
    for (int kk = 0; kk < 2; kk++) {
        bfx8 pf[4], vf[2];
        #pragma unroll
        for (int it = 0; it < 4; it++) pf[it] = *(const bfx8*)&Pl[w][lr + 16 * it][q * 8 + 32 * kk];
        #pragma unroll
        for (int dt = 0; dt < 2; dt++) vf[dt] = *(const bfx8*)&VT[w][lr + 16 * dt][q * 8 + 32 * kk];
        #pragma unroll
        for (int it = 0; it < 4; it++)
            #pragma unroll
            for (int dt = 0; dt < 2; dt++)
                o[it][dt] = __builtin_amdgcn_mfma_f32_16x16x32_bf16(pf[it], vf[dt], o[it][dt], 0, 0, 0);
    }

    u16* ob = outb + (size_t)win * 64 * 256 + head * 32;
    #pragma unroll
    for (int it = 0; it < 4; it++)
        #pragma unroll
        for (int r = 0; r < 4; r++) {
            int i = 16 * it + q * 4 + r;
            u32 pw = pk(o[it][0][r], o[it][1][r]);
            ob[i * 256 + lr]      = (u16)(pw & 0xffff);
            ob[i * 256 + 16 + lr] = (u16)(pw >> 16);
        }
}

// ---------- fused final LayerNorm + [L,C] -> [C,L] transpose (bf16 residual in) ----------
__global__ __launch_bounds__(256) void ln_tr(const u16* __restrict__ in,
                                             const float* __restrict__ g, const float* __restrict__ b,
                                             float* __restrict__ out) {
    __shared__ float tile[256 * 33];
    int tid = threadIdx.x;
    int r   = tid >> 3;
    int cg  = (tid & 7) * 32;
    int row = blockIdx.x * 32 + r;
    const u16* src = in + (size_t)row * 256 + cg;

    float v[32];
    float s1 = 0.f, s2 = 0.f;
    #pragma unroll
    for (int j = 0; j < 4; j++) {
        uint4 f = *(const uint4*)(src + 8 * j);
        u32 ws[4] = {f.x, f.y, f.z, f.w};
        #pragma unroll
        for (int k = 0; k < 4; k++) {
            float a = b2f((u16)(ws[k] & 0xffff));
            float c2 = b2f((u16)(ws[k] >> 16));
            v[8 * j + 2 * k] = a; v[8 * j + 2 * k + 1] = c2;
            s1 += a + c2;
            s2 += a * a + c2 * c2;
        }
    }
    #pragma unroll
    for (int off = 1; off < 8; off <<= 1) { s1 += __shfl_xor(s1, off); s2 += __shfl_xor(s2, off); }
    float mean = s1 * (1.0f / 256.0f);
    float rstd = rsqrtf(s2 * (1.0f / 256.0f) - mean * mean + 1e-5f);

    #pragma unroll
    for (int j = 0; j < 8; j++) {
        float4 gv = *(const float4*)(g + cg + 4 * j);
        float4 bv = *(const float4*)(b + cg + 4 * j);
        int c0 = cg + 4 * j;
        int slot = (r + (c0 >> 2)) & 31;
        tile[(c0 + 0) * 33 + slot] = (v[4*j]   - mean) * rstd * gv.x + bv.x;
        tile[(c0 + 1) * 33 + slot] = (v[4*j+1] - mean) * rstd * gv.y + bv.y;
        tile[(c0 + 2) * 33 + slot] = (v[4*j+2] - mean) * rstd * gv.z + bv.z;
        tile[(c0 + 3) * 33 + slot] = (v[4*j+3] - mean) * rstd * gv.w + bv.w;
    }
    __syncthreads();

    int c = tid;
    int csh = (c >> 2) & 31;
    const float* base = &tile[c * 33];
    float o[32];
    #pragma unroll
    for (int r2 = 0; r2 < 32; r2++) o[r2] = base[(r2 + csh) & 31];

    float* dst = out + (size_t)c * 32768 + blockIdx.x * 32;
    #pragma unroll
    for (int j = 0; j < 8; j++) {
        float4 f; f.x = o[4*j]; f.y = o[4*j+1]; f.z = o[4*j+2]; f.w = o[4*j+3];
        *(float4*)(dst + 4 * j) = f;
    }
}

extern "C" void kernel_launch(void* const* d_in, const int* in_sizes, int n_in,
                              void* d_out, int out_size, void* d_ws, size_t ws_size,
                              hipStream_t stream) {
    const float* x      = (const float*)d_in[0];
    const float* norm_g = (const float*)d_in[4];
    const float* norm_b = (const float*)d_in[5];

    char* wsb = (char*)d_ws;
    u16*   residb = (u16*)wsb;                                    // [0, 16MB)  bf16 residual
    u16*   xn     = (u16*)(wsb + (size_t)32 * 1024 * 1024);       // [32, 48MB) LN output (bf16)
    u16*   big    = (u16*)(wsb + (size_t)48 * 1024 * 1024);       // [48,112MB) qkv (48MB) / fc1 out (64MB)
    u16*   attnb  = (u16*)(wsb + (size_t)96 * 1024 * 1024);       // [96,112MB) attn out (dead before fc1)
    u16*   wb     = (u16*)(wsb + (size_t)112 * 1024 * 1024);      // [112,115MB) bf16 weights

    CvtArgs ca;
    static const int offs[9] = {0, 196608, 262144, 524288, 786432, 983040, 1048576, 1310720, 1572864};
    for (int i = 0; i < 9; i++) ca.cum[i] = offs[i];
    ca.src[0] = (const float*)d_in[6 + 2];   // wqkvw
    ca.src[1] = (const float*)d_in[6 + 5];   // wprojw
    ca.src[2] = (const float*)d_in[6 + 9];   // wfc1w
    ca.src[3] = (const float*)d_in[6 + 11];  // wfc2w
    ca.src[4] = (const float*)d_in[19 + 2];  // sqkvw
    ca.src[5] = (const float*)d_in[19 + 5];  // sprojw
    ca.src[6] = (const float*)d_in[19 + 9];  // sfc1w
    ca.src[7] = (const float*)d_in[19 + 11]; // sfc2w
    cvt_kernel<<<1536, 256, 0, stream>>>(ca, wb);

    for (int blk = 0; blk < 2; blk++) {
        void* const* P = d_in + 6 + blk * 13;
        const float* n1g  = (const float*)P[0];
        const float* n1b  = (const float*)P[1];
        const float* qkvb = (const float*)P[3];
        const float* rpb  = (const float*)P[4];
        const float* pjb  = (const float*)P[6];
        const float* n2g  = (const float*)P[7];
        const float* n2b  = (const float*)P[8];
        const float* f1b  = (const float*)P[10];
        const float* f2b_ = (const float*)P[12];
        const u16* qkvw = wb + offs[0] + blk * 786432;
        const u16* pjw  = wb + offs[1] + blk * 786432;
        const u16* f1w  = wb + offs[2] + blk * 786432;
        const u16* f2w  = wb + offs[3] + blk * 786432;
        int shift = blk ? 2 : 0;

        // blk0: LN1 reads x (fp32) directly; proj epilogue seeds residb = x + proj.
        if (blk == 0) {
            ln_kernel<1, 1><<<8192, 256, 0, stream>>>(x, n1g, n1b, xn, shift);
        } else {
            ln_kernel<1, 0><<<8192, 256, 0, stream>>>(residb, n1g, n1b, xn, shift);
        }
        gemmM<0><<<768, 512, 0, stream>>>(xn, qkvw, qkvb, big, 768, 256);
        attn_mfma<<<2048, 128, 0, stream>>>(big, rpb, attnb, blk);
        if (blk == 0) {
            gemm2<3, 1><<<512, 256, 0, stream>>>(attnb, pjw, pjb, nullptr, residb, 256, 256, shift, x, nullptr);
        } else {
            gemm2<3, 0><<<512, 256, 0, stream>>>(attnb, pjw, pjb, nullptr, residb, 256, 256, shift, nullptr, residb);
        }
        ln_kernel<0, 0><<<8192, 256, 0, stream>>>(residb, n2g, n2b, xn, 0);
        gemm2<1, 0><<<2048, 256, 0, stream>>>(xn, f1w, f1b, big, nullptr, 1024, 256, 0, nullptr, nullptr);
        gemm2<2, 0><<<512, 256, 0, stream>>>(big, f2w, f2b_, nullptr, residb, 256, 1024, 0, nullptr, residb);
    }

    ln_tr<<<1024, 256, 0, stream>>>(residb, norm_g, norm_b, (float*)d_out);
}

// Round 15
// 447.338 us; speedup vs baseline: 1.0454x; 1.0039x over previous
//
#include <hip/hip_runtime.h>

typedef unsigned short u16;
typedef unsigned int   u32;
typedef __bf16 bfx8 __attribute__((ext_vector_type(8)));
typedef float  fx4  __attribute__((ext_vector_type(4)));

// single-instruction packed f32->bf16 (RNE), gfx950
__device__ __forceinline__ u32 pk(float a, float b) {
    u32 r;
    asm("v_cvt_pk_bf16_f32 %0, %1, %2" : "=v"(r) : "v"(a), "v"(b));
    return r;
}
__device__ __forceinline__ u16 f2b(float f) {
    return (u16)pk(f, f);
}
__device__ __forceinline__ float b2f(u16 v) {
    union { u32 i; float f; } u; u.i = ((u32)v) << 16; return u.f;
}

__device__ __forceinline__ void gl2lds16(const u16* g, u16* l) {
    __builtin_amdgcn_global_load_lds(
        (const __attribute__((address_space(1))) u32*)(const void*)g,
        (__attribute__((address_space(3))) u32*)(void*)l, 16, 0, 0);
}

// partitioned row r (window-major) -> token index in [0,32768), with roll shift
__device__ __forceinline__ int map_token(int r, int shift) {
    int win = r >> 6, n = r & 63;
    int wh = win >> 6, ww = (win >> 3) & 7, wt = win & 7;
    int h = wh * 4 + (n >> 4);
    int w = ww * 4 + ((n >> 2) & 3);
    int t = wt * 4 + (n & 3);
    h = (h + shift) & 31; w = (w + shift) & 31; t = (t + shift) & 31;
    return (h << 10) | (w << 5) | t;
}

// fast GELU (tanh form): max abs err ~3e-4, hidden under bf16 output rounding
__device__ __forceinline__ float gelu_fast(float v) {
    float t = v * v;
    float u = v * __builtin_fmaf(t, 0.044715f, 1.0f);
    float e = __expf(-1.5957691216057308f * u);
    return v * __builtin_amdgcn_rcpf(1.0f + e);
}

// ---------- batched fp32 -> bf16 weight conversion ----------
struct CvtArgs { const float* src[8]; int cum[9]; };
__global__ __launch_bounds__(256) void cvt_kernel(CvtArgs a, u16* __restrict__ dst) {
    int g = (blockIdx.x * 256 + threadIdx.x) * 4;
    int t = 0;
    #pragma unroll
    for (int i = 1; i < 8; i++) t += (g >= a.cum[i]);
    int local = g - a.cum[t];
    float4 f = *(const float4*)(a.src[t] + local);
    uint2 o; o.x = pk(f.x, f.y); o.y = pk(f.z, f.w);
    *(uint2*)(dst + g) = o;
}

// ---------- LayerNorm: 2048 blocks, 4 rows per wave (x4 unrolled -> load ILP) ----------
// INF32: input fp32 (only blk0 LN1 reading x); else input bf16 residual.
template<int GATHER, int INF32>
__global__ __launch_bounds__(256) void ln_kernel(const void* __restrict__ inp,
                                                 const float* __restrict__ g, const float* __restrict__ b,
                                                 u16* __restrict__ outp, int shift) {
    int lane = threadIdx.x & 63;
    int wv   = threadIdx.x >> 6;
    int c = lane * 4;
    float4 gv = *(const float4*)(g + c);
    float4 bv = *(const float4*)(b + c);

    int row0 = blockIdx.x * 16 + wv;
    float x[4][4];
    #pragma unroll
    for (int it = 0; it < 4; it++) {
        int row = row0 + it * 4;
        int src = GATHER ? map_token(row, shift) : row;
        if (INF32) {
            float4 xf = ((const float4*)((const float*)inp + (size_t)src * 256))[lane];
            x[it][0] = xf.x; x[it][1] = xf.y; x[it][2] = xf.z; x[it][3] = xf.w;
        } else {
            uint2 xb = ((const uint2*)((const u16*)inp + (size_t)src * 256))[lane];
            x[it][0] = b2f((u16)(xb.x & 0xffff)); x[it][1] = b2f((u16)(xb.x >> 16));
            x[it][2] = b2f((u16)(xb.y & 0xffff)); x[it][3] = b2f((u16)(xb.y >> 16));
        }
    }
    #pragma unroll
    for (int it = 0; it < 4; it++) {
        float s1 = x[it][0] + x[it][1] + x[it][2] + x[it][3];
        float s2 = x[it][0]*x[it][0] + x[it][1]*x[it][1] + x[it][2]*x[it][2] + x[it][3]*x[it][3];
        #pragma unroll
        for (int off = 1; off < 64; off <<= 1) { s1 += __shfl_xor(s1, off); s2 += __shfl_xor(s2, off); }
        float mean = s1 * (1.0f / 256.0f);
        float rstd = rsqrtf(s2 * (1.0f / 256.0f) - mean * mean + 1e-5f);
        uint2 o;
        o.x = pk((x[it][0] - mean) * rstd * gv.x + bv.x, (x[it][1] - mean) * rstd * gv.y + bv.y);
        o.y = pk((x[it][2] - mean) * rstd * gv.z + bv.z, (x[it][3] - mean) * rstd * gv.w + bv.w);
        int row = row0 + it * 4;
        *(uint2*)(outp + (size_t)row * 256 + c) = o;
    }
}

// ---------- GEMM-128: C[M,N] = A[M,K] @ W[N,K]^T + bias ----------
// 128x128 tile, BK=32, 256 thr / 4 waves. 3-buf depth-2 gl2lds pipeline, one
// barrier per step, counted vmcnt(4). XCD swizzle: xcd=bid&7 owns m-tiles
// [xcd*32,+32), n outer. Used for proj / fc1 / fc2.
// EPI 0: bf16 store; 1: GELU + bf16 store; 2/3: residb[row] = rsrc[row] + v
// (bf16 residual stream; RSF32=1 -> rsrc is fp32 x, else bf16 residb)
template<int EPI, int RSF32>
__global__ __launch_bounds__(256) void gemm2(const u16* __restrict__ A, const u16* __restrict__ W,
                                             const float* __restrict__ bias,
                                             u16* __restrict__ outb, u16* __restrict__ residb,
                                             int Nout, int K, int shift,
                                             const float* __restrict__ rsrcf, const u16* __restrict__ rsrcb) {
    __shared__ u16 As[3][4096];
    __shared__ u16 Bs[3][4096];
    int lane = threadIdx.x & 63, w = threadIdx.x >> 6;
    int wm = w >> 1, wn = w & 1;
    int bid = blockIdx.x;
    int xcd = bid & 7;
    int s   = bid >> 3;
    int m0 = (xcd * 32 + (s & 31)) * 128;
    int n0 = (s >> 5) * 128;
    int lr = lane & 15, q = lane >> 4;
    int sw = q ^ ((lr >> 1) & 3);

    int rowS  = w * 16 + (lane >> 2);
    int kg    = (lane & 3) ^ ((rowS >> 1) & 3);
    int slot0 = (w * 64 + lane) * 8;
    int slot1 = slot0 + 2048;
    const u16* gA0 = A + (size_t)(m0 + rowS) * K + kg * 8;
    const u16* gA1 = A + (size_t)(m0 + rowS + 64) * K + kg * 8;
    const u16* gB0 = W + (size_t)(n0 + rowS) * K + kg * 8;
    const u16* gB1 = W + (size_t)(n0 + rowS + 64) * K + kg * 8;

    int oA[4], oB[4];
    #pragma unroll
    for (int t = 0; t < 4; t++) {
        oA[t] = ((wm * 64 + t * 16 + lr) * 4 + sw) * 8;
        oB[t] = ((wn * 64 + t * 16 + lr) * 4 + sw) * 8;
    }

    fx4 acc[4][4] = {};

    auto stage = [&](int kt, int b) {
        gl2lds16(gA0 + kt, &As[b][slot0]);
        gl2lds16(gA1 + kt, &As[b][slot1]);
        gl2lds16(gB0 + kt, &Bs[b][slot0]);
        gl2lds16(gB1 + kt, &Bs[b][slot1]);
    };

    int nk = K >> 5;
    stage(0, 0);
    if (nk > 1) stage(32, 1);
    int b0 = 0, b1 = 1, b2 = 2;
    for (int ki = 0; ki < nk; ki++) {
        if (ki + 1 < nk) asm volatile("s_waitcnt vmcnt(4)" ::: "memory");
        else             asm volatile("s_waitcnt vmcnt(0)" ::: "memory");
        __builtin_amdgcn_s_barrier();
        __builtin_amdgcn_sched_barrier(0);
        if (ki + 2 < nk) stage((ki + 2) << 5, b2);
        bfx8 af[4], bfr[4];
        #pragma unroll
        for (int t = 0; t < 4; t++) {
            af[t]  = *(const bfx8*)(&As[b0][oA[t]]);
            bfr[t] = *(const bfx8*)(&Bs[b0][oB[t]]);
        }
        #pragma unroll
        for (int i = 0; i < 4; i++)
            #pragma unroll
            for (int j = 0; j < 4; j++)
                acc[i][j] = __builtin_amdgcn_mfma_f32_16x16x32_bf16(af[i], bfr[j], acc[i][j], 0, 0, 0);
        int tmp = b0; b0 = b1; b1 = b2; b2 = tmp;
    }

    float bv[4];
    #pragma unroll
    for (int j = 0; j < 4; j++) bv[j] = bias[n0 + wn * 64 + j * 16 + lr];
    #pragma unroll
    for (int i = 0; i < 4; i++) {
        #pragma unroll
        for (int r = 0; r < 4; r++) {
            int gr = m0 + wm * 64 + i * 16 + q * 4 + r;
            int orow = (EPI == 3) ? map_token(gr, shift) : gr;
            #pragma unroll
            for (int j = 0; j < 4; j++) {
                int gc = n0 + wn * 64 + j * 16 + lr;
                float v = acc[i][j][r] + bv[j];
                if (EPI == 0) {
                    outb[(size_t)gr * Nout + gc] = f2b(v);
                } else if (EPI == 1) {
                    outb[(size_t)gr * Nout + gc] = f2b(gelu_fast(v));
                } else {
                    float rv = RSF32 ? rsrcf[orow * 256 + gc] : b2f(rsrcb[orow * 256 + gc]);
                    residb[orow * 256 + gc] = f2b(rv + v);
                }
            }
        }
    }
}

// ---------- GEMM-256: BM=256 x BN=128, BK=32, 512 thr / 8 waves (4m x 2n) ----------
// Same 3-buf one-barrier counted-vmcnt core; 3 gl2lds/stage -> vmcnt(3).
// XCD swizzle: xcd owns m-tiles [xcd*16,+16), n outer. Used for qkv (Nout=768).
template<int EPI>
__global__ __launch_bounds__(512) void gemmM(const u16* __restrict__ A, const u16* __restrict__ W,
                                             const float* __restrict__ bias,
                                             u16* __restrict__ outb, int Nout, int K) {
    __shared__ u16 As[3][8192];   // 256 rows x 32 cols
    __shared__ u16 Bs[3][4096];   // 128 rows x 32 cols
    int tid = threadIdx.x;
    int lane = tid & 63, w = tid >> 6;
    int wm = w >> 1, wn = w & 1;
    int bid = blockIdx.x;
    int xcd = bid & 7;
    int s   = bid >> 3;
    int m0 = (xcd * 16 + (s & 15)) * 256;
    int n0 = (s >> 4) * 128;
    int lr = lane & 15, q = lane >> 4;
    int sw = q ^ ((lr >> 1) & 3);

    int rowS  = tid >> 2;
    int kg    = (tid & 3) ^ ((rowS >> 1) & 3);
    int slotS = tid * 8;
    const u16* gA0 = A + (size_t)(m0 + rowS) * K + kg * 8;
    const u16* gA1 = A + (size_t)(m0 + rowS + 128) * K + kg * 8;
    const u16* gB0 = W + (size_t)(n0 + rowS) * K + kg * 8;

    int oA[4], oB[4];
    #pragma unroll
    for (int t = 0; t < 4; t++) {
        oA[t] = ((wm * 64 + t * 16 + lr) * 4 + sw) * 8;
        oB[t] = ((wn * 64 + t * 16 + lr) * 4 + sw) * 8;
    }

    fx4 acc[4][4] = {};

    auto stage = [&](int kt, int b) {
        gl2lds16(gA0 + kt, &As[b][slotS]);
        gl2lds16(gA1 + kt, &As[b][slotS + 4096]);
        gl2lds16(gB0 + kt, &Bs[b][slotS]);
    };

    int nk = K >> 5;
    stage(0, 0);
    if (nk > 1) stage(32, 1);
    int b0 = 0, b1 = 1, b2 = 2;
    for (int ki = 0; ki < nk; ki++) {
        if (ki + 1 < nk) asm volatile("s_waitcnt vmcnt(3)" ::: "memory");
        else             asm volatile("s_waitcnt vmcnt(0)" ::: "memory");
        __builtin_amdgcn_s_barrier();
        __builtin_amdgcn_sched_barrier(0);
        if (ki + 2 < nk) stage((ki + 2) << 5, b2);
        bfx8 af[4], bfr[4];
        #pragma unroll
        for (int t = 0; t < 4; t++) {
            af[t]  = *(const bfx8*)(&As[b0][oA[t]]);
            bfr[t] = *(const bfx8*)(&Bs[b0][oB[t]]);
        }
        #pragma unroll
        for (int i = 0; i < 4; i++)
            #pragma unroll
            for (int j = 0; j < 4; j++)
                acc[i][j] = __builtin_amdgcn_mfma_f32_16x16x32_bf16(af[i], bfr[j], acc[i][j], 0, 0, 0);
        int tmp = b0; b0 = b1; b1 = b2; b2 = tmp;
    }

    float bv[4];
    #pragma unroll
    for (int j = 0; j < 4; j++) bv[j] = bias[n0 + wn * 64 + j * 16 + lr];
    #pragma unroll
    for (int i = 0; i < 4; i++) {
        #pragma unroll
        for (int r = 0; r < 4; r++) {
            int gr = m0 + wm * 64 + i * 16 + q * 4 + r;
            #pragma unroll
            for (int j = 0; j < 4; j++) {
                int gc = n0 + wn * 64 + j * 16 + lr;
                float v = acc[i][j][r] + bv[j];
                outb[(size_t)gr * Nout + gc] = f2b(EPI == 1 ? gelu_fast(v) : v);
            }
        }
    }
}

// ---------- MFMA attention: one wave per (window, head), 2 waves/block ----------
__global__ __launch_bounds__(128) void attn_mfma(const u16* __restrict__ qkv, const float* __restrict__ rpb,
                                                 u16* __restrict__ outb, int masked) {
    __shared__ u16  Pl[2][64][72];
    __shared__ u16  VT[2][32][72];
    __shared__ float rbS[2][344];
    int w = threadIdx.x >> 6;
    int lane = threadIdx.x & 63;
    int id = blockIdx.x * 2 + w;
    int win = id >> 3, head = id & 7;
    int lr = lane & 15, q = lane >> 4;

    const u16* base = qkv + (size_t)win * 64 * 768 + head * 32;

    bfx8 qf[4], kf[4];
    #pragma unroll
    for (int t = 0; t < 4; t++) {
        const u16* rq = base + (lr + 16 * t) * 768 + q * 8;
        qf[t] = *(const bfx8*)(rq);
        kf[t] = *(const bfx8*)(rq + 256);
    }
    {
        const u16* rv = base + lane * 768 + 512;
        #pragma unroll
        for (int c = 0; c < 32; c += 8) {
            bfx8 vv = *(const bfx8*)(rv + c);
            #pragma unroll
            for (int j = 0; j < 8; j++) VT[w][c + j][lane] = ((const u16*)&vv)[j];
        }
    }
    for (int i = lane; i < 343; i += 64) rbS[w][i] = rpb[i * 8 + head];

    fx4 sT[4][4] = {};
    #pragma unroll
    for (int jt = 0; jt < 4; jt++)
        #pragma unroll
        for (int it = 0; it < 4; it++)
            sT[jt][it] = __builtin_amdgcn_mfma_f32_16x16x32_bf16(kf[jt], qf[it], sT[jt][it], 0, 0, 0);

    int wh = win >> 6, ww = (win >> 3) & 7, wt = win & 7;
    const float scale = 0.17677669529663687f;   // hd^-0.5

    #pragma unroll
    for (int it = 0; it < 4; it++) {
        int i = lr + 16 * it;
        int ih = i >> 4, iw = (i >> 2) & 3, iT = i & 3;
        int labn = 0;
        if (masked) {
            int lh = (wh == 7) ? (1 + (ih >> 1)) : 0;
            int lw = (ww == 7) ? (1 + (iw >> 1)) : 0;
            int lt = (wt == 7) ? (1 + (iT >> 1)) : 0;
            labn = lh * 9 + lw * 3 + lt;
        }
        float sv[4][4];
        float mx = -1e30f;
        #pragma unroll
        for (int jt = 0; jt < 4; jt++)
            #pragma unroll
            for (int r = 0; r < 4; r++) {
                int j = q * 4 + r + 16 * jt;
                int jh = j >> 4, jw = (j >> 2) & 3, jT = j & 3;
                float s = sT[jt][it][r] * scale +
                          rbS[w][((ih - jh + 3) * 7 + (iw - jw + 3)) * 7 + (iT - jT + 3)];
                if (masked) {
                    int lh = (wh == 7) ? (1 + (jh >> 1)) : 0;
                    int lw = (ww == 7) ? (1 + (jw >> 1)) : 0;
                    int lt = (wt == 7) ? (1 + (jT >> 1)) : 0;
                    if (lh * 9 + lw * 3 + lt != labn) s -= 100.0f;
                }
                sv[jt][r] = s;
                mx = fmaxf(mx, s);
            }
        mx = fmaxf(mx, __shfl_xor(mx, 16));
        mx = fmaxf(mx, __shfl_xor(mx, 32));
        float sum = 0.f;
        #pragma unroll
        for (int jt = 0; jt < 4; jt++)
            #pragma unroll
            for (int r = 0; r < 4; r++) { sv[jt][r] = __expf(sv[jt][r] - mx); sum += sv[jt][r]; }
        sum += __shfl_xor(sum, 16);
        sum += __shfl_xor(sum, 32);
        float inv = 1.0f / sum;
        #pragma unroll
        for (int jt = 0; jt < 4; jt++) {
            uint2 pw;
            pw.x = pk(sv[jt][0] * inv, sv[jt][1] * inv);
            pw.y = pk(sv[jt][2] * inv, sv[jt][3] * inv);
            *(uint2*)&Pl[w][i][q * 4 + 16 * jt] = pw;
        }
    }

    fx4 o[4][2] = {};
    #pragma unroll
    for (int kk = 0; kk < 2; kk++) {
        bfx8 pf[4], vf[2];
        #pragma unroll
        for (int it = 0; it < 4; it++) pf[it] = *(const bfx8*)&Pl[w][lr + 16 * it][q * 8 + 32 * kk];
        #pragma unroll
        for (int dt = 0; dt < 2; dt++) vf[dt] = *(const bfx8*)&VT[w][lr + 16 * dt][q * 8 + 32 * kk];
        #pragma unroll
        for (int it = 0; it < 4; it++)
            #pragma unroll
            for (int dt = 0; dt < 2; dt++)
                o[it][dt] = __builtin_amdgcn_mfma_f32_16x16x32_bf16(pf[it], vf[dt], o[it][dt], 0, 0, 0);
    }

    u16* ob = outb + (size_t)win * 64 * 256 + head * 32;
    #pragma unroll
    for (int it = 0; it < 4; it++)
        #pragma unroll
        for (int r = 0; r < 4; r++) {
            int i = 16 * it + q * 4 + r;
            u32 pw = pk(o[it][0][r], o[it][1][r]);
            ob[i * 256 + lr]      = (u16)(pw & 0xffff);
            ob[i * 256 + 16 + lr] = (u16)(pw >> 16);
        }
}

// ---------- fused final LayerNorm + [L,C] -> [C,L] transpose (bf16 residual in) ----------
__global__ __launch_bounds__(256) void ln_tr(const u16* __restrict__ in,
                                             const float* __restrict__ g, const float* __restrict__ b,
                                             float* __restrict__ out) {
    __shared__ float tile[256 * 33];
    int tid = threadIdx.x;
    int r   = tid >> 3;
    int cg  = (tid & 7) * 32;
    int row = blockIdx.x * 32 + r;
    const u16* src = in + (size_t)row * 256 + cg;

    float v[32];
    float s1 = 0.f, s2 = 0.f;
    #pragma unroll
    for (int j = 0; j < 4; j++) {
        uint4 f = *(const uint4*)(src + 8 * j);
        u32 ws[4] = {f.x, f.y, f.z, f.w};
        #pragma unroll
        for (int k = 0; k < 4; k++) {
            float a = b2f((u16)(ws[k] & 0xffff));
            float c2 = b2f((u16)(ws[k] >> 16));
            v[8 * j + 2 * k] = a; v[8 * j + 2 * k + 1] = c2;
            s1 += a + c2;
            s2 += a * a + c2 * c2;
        }
    }
    #pragma unroll
    for (int off = 1; off < 8; off <<= 1) { s1 += __shfl_xor(s1, off); s2 += __shfl_xor(s2, off); }
    float mean = s1 * (1.0f / 256.0f);
    float rstd = rsqrtf(s2 * (1.0f / 256.0f) - mean * mean + 1e-5f);

    #pragma unroll
    for (int j = 0; j < 8; j++) {
        float4 gv = *(const float4*)(g + cg + 4 * j);
        float4 bv = *(const float4*)(b + cg + 4 * j);
        int c0 = cg + 4 * j;
        int slot = (r + (c0 >> 2)) & 31;
        tile[(c0 + 0) * 33 + slot] = (v[4*j]   - mean) * rstd * gv.x + bv.x;
        tile[(c0 + 1) * 33 + slot] = (v[4*j+1] - mean) * rstd * gv.y + bv.y;
        tile[(c0 + 2) * 33 + slot] = (v[4*j+2] - mean) * rstd * gv.z + bv.z;
        tile[(c0 + 3) * 33 + slot] = (v[4*j+3] - mean) * rstd * gv.w + bv.w;
    }
    __syncthreads();

    int c = tid;
    int csh = (c >> 2) & 31;
    const float* base = &tile[c * 33];
    float o[32];
    #pragma unroll
    for (int r2 = 0; r2 < 32; r2++) o[r2] = base[(r2 + csh) & 31];

    float* dst = out + (size_t)c * 32768 + blockIdx.x * 32;
    #pragma unroll
    for (int j = 0; j < 8; j++) {
        float4 f; f.x = o[4*j]; f.y = o[4*j+1]; f.z = o[4*j+2]; f.w = o[4*j+3];
        *(float4*)(dst + 4 * j) = f;
    }
}

extern "C" void kernel_launch(void* const* d_in, const int* in_sizes, int n_in,
                              void* d_out, int out_size, void* d_ws, size_t ws_size,
                              hipStream_t stream) {
    const float* x      = (const float*)d_in[0];
    const float* norm_g = (const float*)d_in[4];
    const float* norm_b = (const float*)d_in[5];

    char* wsb = (char*)d_ws;
    u16*   residb = (u16*)wsb;                                    // [0, 16MB)  bf16 residual
    u16*   xn     = (u16*)(wsb + (size_t)32 * 1024 * 1024);       // [32, 48MB) LN output (bf16)
    u16*   big    = (u16*)(wsb + (size_t)48 * 1024 * 1024);       // [48,112MB) qkv (48MB) / fc1 out (64MB)
    u16*   attnb  = (u16*)(wsb + (size_t)96 * 1024 * 1024);       // [96,112MB) attn out (dead before fc1)
    u16*   wb     = (u16*)(wsb + (size_t)112 * 1024 * 1024);      // [112,115MB) bf16 weights

    CvtArgs ca;
    static const int offs[9] = {0, 196608, 262144, 524288, 786432, 983040, 1048576, 1310720, 1572864};
    for (int i = 0; i < 9; i++) ca.cum[i] = offs[i];
    ca.src[0] = (const float*)d_in[6 + 2];   // wqkvw
    ca.src[1] = (const float*)d_in[6 + 5];   // wprojw
    ca.src[2] = (const float*)d_in[6 + 9];   // wfc1w
    ca.src[3] = (const float*)d_in[6 + 11];  // wfc2w
    ca.src[4] = (const float*)d_in[19 + 2];  // sqkvw
    ca.src[5] = (const float*)d_in[19 + 5];  // sprojw
    ca.src[6] = (const float*)d_in[19 + 9];  // sfc1w
    ca.src[7] = (const float*)d_in[19 + 11]; // sfc2w
    cvt_kernel<<<1536, 256, 0, stream>>>(ca, wb);

    for (int blk = 0; blk < 2; blk++) {
        void* const* P = d_in + 6 + blk * 13;
        const float* n1g  = (const float*)P[0];
        const float* n1b  = (const float*)P[1];
        const float* qkvb = (const float*)P[3];
        const float* rpb  = (const float*)P[4];
        const float* pjb  = (const float*)P[6];
        const float* n2g  = (const float*)P[7];
        const float* n2b  = (const float*)P[8];
        const float* f1b  = (const float*)P[10];
        const float* f2b_ = (const float*)P[12];
        const u16* qkvw = wb + offs[0] + blk * 786432;
        const u16* pjw  = wb + offs[1] + blk * 786432;
        const u16* f1w  = wb + offs[2] + blk * 786432;
        const u16* f2w  = wb + offs[3] + blk * 786432;
        int shift = blk ? 2 : 0;

        // blk0: LN1 reads x (fp32) directly; proj epilogue seeds residb = x + proj.
        if (blk == 0) {
            ln_kernel<1, 1><<<2048, 256, 0, stream>>>(x, n1g, n1b, xn, shift);
        } else {
            ln_kernel<1, 0><<<2048, 256, 0, stream>>>(residb, n1g, n1b, xn, shift);
        }
        gemmM<0><<<768, 512, 0, stream>>>(xn, qkvw, qkvb, big, 768, 256);
        attn_mfma<<<2048, 128, 0, stream>>>(big, rpb, attnb, blk);
        if (blk == 0) {
            gemm2<3, 1><<<512, 256, 0, stream>>>(attnb, pjw, pjb, nullptr, residb, 256, 256, shift, x, nullptr);
        } else {
            gemm2<3, 0><<<512, 256, 0, stream>>>(attnb, pjw, pjb, nullptr, residb, 256, 256, shift, nullptr, residb);
        }
        ln_kernel<0, 0><<<2048, 256, 0, stream>>>(residb, n2g, n2b, xn, 0);
        gemm2<1, 0><<<2048, 256, 0, stream>>>(xn, f1w, f1b, big, nullptr, 1024, 256, 0, nullptr, nullptr);
        gemm2<2, 0><<<512, 256, 0, stream>>>(big, f2w, f2b_, nullptr, residb, 256, 1024, 0, nullptr, residb);
    }

    ln_tr<<<1024, 256, 0, stream>>>(residb, norm_g, norm_b, (float*)d_out);
}